// Round 1
// baseline (1503.999 us; speedup 1.0000x reference)
//
#include <hip/hip_runtime.h>
#include <hip/hip_bf16.h>

#define HID  2048
#define NEXP 8
#define FINT 1408
#define BM   128
#define BN   128
#define BK   32
#define PITCH 40   // bf16 elems per LDS row (80B) -> conflict-free b128 access

typedef __bf16 bf16_t;
typedef __bf16 bf16x8 __attribute__((ext_vector_type(8)));
typedef float  f32x4  __attribute__((ext_vector_type(4)));

// ---------------- router: logits -> softmax -> top2 + counts ----------------
__global__ __launch_bounds__(64) void router_kernel(
    const float* __restrict__ x, const float* __restrict__ gw,
    int* __restrict__ cnt, int* __restrict__ topk_id, float* __restrict__ topk_w, int T)
{
    int t = blockIdx.x;
    if (t >= T) return;
    int lane = threadIdx.x;
    float acc[NEXP];
#pragma unroll
    for (int e = 0; e < NEXP; ++e) acc[e] = 0.f;
    const float* xr = x + (size_t)t * HID;
    for (int i = lane; i < HID; i += 64) {
        float xv = xr[i];
        const float4* g4 = (const float4*)(gw + (size_t)i * NEXP);
        float4 a = g4[0], b = g4[1];
        acc[0] += xv * a.x; acc[1] += xv * a.y; acc[2] += xv * a.z; acc[3] += xv * a.w;
        acc[4] += xv * b.x; acc[5] += xv * b.y; acc[6] += xv * b.z; acc[7] += xv * b.w;
    }
#pragma unroll
    for (int d = 1; d < 64; d <<= 1) {
#pragma unroll
        for (int e = 0; e < NEXP; ++e) acc[e] += __shfl_xor(acc[e], d, 64);
    }
    float mx = acc[0];
#pragma unroll
    for (int e = 1; e < NEXP; ++e) mx = fmaxf(mx, acc[e]);
    float p[NEXP]; float s = 0.f;
#pragma unroll
    for (int e = 0; e < NEXP; ++e) { p[e] = expf(acc[e] - mx); s += p[e]; }
    float inv = 1.f / s;
    int i1 = 0;
#pragma unroll
    for (int e = 1; e < NEXP; ++e) if (acc[e] > acc[i1]) i1 = e;   // strict > : lowest idx on tie
    int i2 = (i1 == 0) ? 1 : 0;
#pragma unroll
    for (int e = 0; e < NEXP; ++e) if (e != i1 && acc[e] > acc[i2]) i2 = e;
    if (lane == 0) {
        topk_id[t * 2 + 0] = i1; topk_id[t * 2 + 1] = i2;
        topk_w[t * 2 + 0] = p[i1] * inv; topk_w[t * 2 + 1] = p[i2] * inv;
        atomicAdd(&cnt[i1], 1); atomicAdd(&cnt[i2], 1);
    }
}

__global__ void offsets_kernel(const int* __restrict__ cnt, int* __restrict__ offs)
{
    if (threadIdx.x == 0) {
        int s = 0;
        for (int e = 0; e < NEXP; ++e) { offs[e] = s; s += cnt[e]; }
        offs[NEXP] = s;
    }
}

__global__ void scatter_kernel(
    const int* __restrict__ topk_id, const float* __restrict__ topk_w,
    const int* __restrict__ offs, int* __restrict__ fill,
    int* __restrict__ tok, float* __restrict__ wslot, int* __restrict__ slot_of, int T)
{
    int t = blockIdx.x * blockDim.x + threadIdx.x;
    if (t >= T) return;
#pragma unroll
    for (int k = 0; k < 2; ++k) {
        int e = topk_id[t * 2 + k];
        int pos = atomicAdd(&fill[e], 1);
        int slot = offs[e] + pos;
        tok[slot] = t;
        wslot[slot] = topk_w[t * 2 + k];
        slot_of[t * 2 + k] = slot;
    }
}

// ---------------- gate+up fused GEMM -> silu(g)*u -> h (bf16) ----------------
__global__ __launch_bounds__(256) void gateup_kernel(
    const float* __restrict__ x, const float* __restrict__ wg, const float* __restrict__ wu,
    const int* __restrict__ offs, const int* __restrict__ tok,
    bf16_t* __restrict__ h_buf, int maxTiles)
{
    int e = blockIdx.x / maxTiles;
    int tr = blockIdx.x - e * maxTiles;
    int seg0 = offs[e];
    int nseg = offs[e + 1] - seg0;
    int rbase = tr * BM;
    if (rbase >= nseg) return;
    int nvalid = nseg - rbase; if (nvalid > BM) nvalid = BM;
    int row0 = seg0 + rbase;
    int f0 = blockIdx.y * BN;

    __shared__ bf16_t As[BM * PITCH];
    __shared__ bf16_t Bgs[BN * PITCH];
    __shared__ bf16_t Bus[BN * PITCH];

    int tid = threadIdx.x;
    int lane = tid & 63, wid = tid >> 6;
    int wm = wid >> 1, wn = wid & 1;
    int lr = lane & 15, lg = lane >> 4;

    // staging roles
    int a_r = tid >> 1;             // row (token slot within tile)
    int a_k = (tid & 1) * 16;       // k-half
    int tkn = (a_r < nvalid) ? tok[row0 + a_r] : 0;
    const float* aptr = x + (size_t)tkn * HID + a_k;

    int b_n = tid & (BN - 1);       // f column
    int b_k = (tid >> 7) * 16;      // k-half
    const float* gptr = wg + (size_t)e * HID * FINT + (size_t)b_k * FINT + f0 + b_n;
    const float* uptr = wu + (size_t)e * HID * FINT + (size_t)b_k * FINT + f0 + b_n;

    f32x4 zero = {0.f, 0.f, 0.f, 0.f};
    f32x4 accg[4][4], accu[4][4];
#pragma unroll
    for (int i = 0; i < 4; ++i)
#pragma unroll
        for (int j = 0; j < 4; ++j) { accg[i][j] = zero; accu[i][j] = zero; }

    float ar[16], bgr[16], bur[16];

    auto load_stage = [&](int kt) {
        const float4* a4 = (const float4*)(aptr + (size_t)kt * BK);
#pragma unroll
        for (int i = 0; i < 4; ++i) {
            float4 v = a4[i];
            ar[i * 4 + 0] = v.x; ar[i * 4 + 1] = v.y; ar[i * 4 + 2] = v.z; ar[i * 4 + 3] = v.w;
        }
        const float* gp = gptr + (size_t)kt * BK * FINT;
        const float* up = uptr + (size_t)kt * BK * FINT;
#pragma unroll
        for (int i = 0; i < 16; ++i) { bgr[i] = gp[(size_t)i * FINT]; bur[i] = up[(size_t)i * FINT]; }
    };
    auto write_stage = [&]() {
        bf16x8 w0, w1;
#pragma unroll
        for (int j = 0; j < 8; ++j) { w0[j] = (bf16_t)ar[j]; w1[j] = (bf16_t)ar[8 + j]; }
        *(bf16x8*)&As[a_r * PITCH + a_k] = w0;
        *(bf16x8*)&As[a_r * PITCH + a_k + 8] = w1;
#pragma unroll
        for (int j = 0; j < 8; ++j) { w0[j] = (bf16_t)bgr[j]; w1[j] = (bf16_t)bgr[8 + j]; }
        *(bf16x8*)&Bgs[b_n * PITCH + b_k] = w0;
        *(bf16x8*)&Bgs[b_n * PITCH + b_k + 8] = w1;
#pragma unroll
        for (int j = 0; j < 8; ++j) { w0[j] = (bf16_t)bur[j]; w1[j] = (bf16_t)bur[8 + j]; }
        *(bf16x8*)&Bus[b_n * PITCH + b_k] = w0;
        *(bf16x8*)&Bus[b_n * PITCH + b_k + 8] = w1;
    };
    auto compute = [&]() {
        bf16x8 a[4];
#pragma unroll
        for (int mi = 0; mi < 4; ++mi)
            a[mi] = *(const bf16x8*)&As[(wm * 64 + mi * 16 + lr) * PITCH + lg * 8];
#pragma unroll
        for (int ni = 0; ni < 4; ++ni) {
            bf16x8 bg = *(const bf16x8*)&Bgs[(wn * 64 + ni * 16 + lr) * PITCH + lg * 8];
            bf16x8 bu = *(const bf16x8*)&Bus[(wn * 64 + ni * 16 + lr) * PITCH + lg * 8];
#pragma unroll
            for (int mi = 0; mi < 4; ++mi) {
                accg[mi][ni] = __builtin_amdgcn_mfma_f32_16x16x32_bf16(a[mi], bg, accg[mi][ni], 0, 0, 0);
                accu[mi][ni] = __builtin_amdgcn_mfma_f32_16x16x32_bf16(a[mi], bu, accu[mi][ni], 0, 0, 0);
            }
        }
    };

    const int NK = HID / BK;   // 64
    load_stage(0);
    for (int kt = 0; kt < NK; ++kt) {
        __syncthreads();
        write_stage();
        __syncthreads();
        if (kt + 1 < NK) load_stage(kt + 1);   // global loads overlap compute
        compute();
    }

    // epilogue: h = silu(g) * u
#pragma unroll
    for (int mi = 0; mi < 4; ++mi) {
        int rb = wm * 64 + mi * 16 + lg * 4;
#pragma unroll
        for (int ni = 0; ni < 4; ++ni) {
            int col = f0 + wn * 64 + ni * 16 + lr;
#pragma unroll
            for (int r = 0; r < 4; ++r) {
                int row = rb + r;
                if (row < nvalid) {
                    float g = accg[mi][ni][r], u = accu[mi][ni][r];
                    float h = (g / (1.f + __expf(-g))) * u;
                    h_buf[(size_t)(row0 + row) * FINT + col] = (bf16_t)h;
                }
            }
        }
    }
}

// ---------------- down GEMM -> per-slot y (bf16) or atomic scatter ----------------
__global__ __launch_bounds__(256) void down_kernel(
    const bf16_t* __restrict__ h_buf, const float* __restrict__ wd,
    const int* __restrict__ offs, const int* __restrict__ tok, const float* __restrict__ wslot,
    float* __restrict__ out, bf16_t* __restrict__ y_buf, int useY, int maxTiles)
{
    int e = blockIdx.x / maxTiles;
    int tr = blockIdx.x - e * maxTiles;
    int seg0 = offs[e];
    int nseg = offs[e + 1] - seg0;
    int rbase = tr * BM;
    if (rbase >= nseg) return;
    int nvalid = nseg - rbase; if (nvalid > BM) nvalid = BM;
    int row0 = seg0 + rbase;
    int h0 = blockIdx.y * BN;

    __shared__ bf16_t As[BM * PITCH];
    __shared__ bf16_t Bs[BN * PITCH];
    __shared__ float wsh[BM];
    __shared__ int   tsh[BM];

    int tid = threadIdx.x;
    if (tid < BM) {
        int v = tid < nvalid;
        wsh[tid] = v ? wslot[row0 + tid] : 0.f;
        tsh[tid] = v ? tok[row0 + tid] : 0;
    }

    int lane = tid & 63, wid = tid >> 6;
    int wm = wid >> 1, wn = wid & 1;
    int lr = lane & 15, lg = lane >> 4;

    int a_r = tid >> 1;
    int a_k = (tid & 1) * 16;
    const bf16_t* aptr = h_buf + (size_t)(row0 + a_r) * FINT + a_k;

    int b_n = tid & (BN - 1);
    int b_k = (tid >> 7) * 16;
    const float* dptr = wd + (size_t)e * FINT * HID + (size_t)b_k * HID + h0 + b_n;

    f32x4 zero = {0.f, 0.f, 0.f, 0.f};
    f32x4 acc[4][4];
#pragma unroll
    for (int i = 0; i < 4; ++i)
#pragma unroll
        for (int j = 0; j < 4; ++j) acc[i][j] = zero;

    bf16x8 ar0, ar1; float br[16];
    auto load_stage = [&](int kt) {
        const bf16x8* a8 = (const bf16x8*)(aptr + (size_t)kt * BK);
        ar0 = a8[0]; ar1 = a8[1];
        const float* dp = dptr + (size_t)kt * BK * HID;
#pragma unroll
        for (int i = 0; i < 16; ++i) br[i] = dp[(size_t)i * HID];
    };
    auto write_stage = [&]() {
        *(bf16x8*)&As[a_r * PITCH + a_k] = ar0;
        *(bf16x8*)&As[a_r * PITCH + a_k + 8] = ar1;
        bf16x8 w0, w1;
#pragma unroll
        for (int j = 0; j < 8; ++j) { w0[j] = (bf16_t)br[j]; w1[j] = (bf16_t)br[8 + j]; }
        *(bf16x8*)&Bs[b_n * PITCH + b_k] = w0;
        *(bf16x8*)&Bs[b_n * PITCH + b_k + 8] = w1;
    };
    auto compute = [&]() {
        bf16x8 a[4];
#pragma unroll
        for (int mi = 0; mi < 4; ++mi)
            a[mi] = *(const bf16x8*)&As[(wm * 64 + mi * 16 + lr) * PITCH + lg * 8];
#pragma unroll
        for (int ni = 0; ni < 4; ++ni) {
            bf16x8 b = *(const bf16x8*)&Bs[(wn * 64 + ni * 16 + lr) * PITCH + lg * 8];
#pragma unroll
            for (int mi = 0; mi < 4; ++mi)
                acc[mi][ni] = __builtin_amdgcn_mfma_f32_16x16x32_bf16(a[mi], b, acc[mi][ni], 0, 0, 0);
        }
    };

    const int NK = FINT / BK;  // 44
    load_stage(0);
    for (int kt = 0; kt < NK; ++kt) {
        __syncthreads();
        write_stage();
        __syncthreads();
        if (kt + 1 < NK) load_stage(kt + 1);
        compute();
    }

    if (useY) {
#pragma unroll
        for (int mi = 0; mi < 4; ++mi) {
            int rb = wm * 64 + mi * 16 + lg * 4;
#pragma unroll
            for (int ni = 0; ni < 4; ++ni) {
                int col = h0 + wn * 64 + ni * 16 + lr;
#pragma unroll
                for (int r = 0; r < 4; ++r) {
                    int row = rb + r;
                    if (row < nvalid)
                        y_buf[(size_t)(row0 + row) * HID + col] = (bf16_t)acc[mi][ni][r];
                }
            }
        }
    } else {
#pragma unroll
        for (int mi = 0; mi < 4; ++mi) {
            int rb = wm * 64 + mi * 16 + lg * 4;
#pragma unroll
            for (int ni = 0; ni < 4; ++ni) {
                int col = h0 + wn * 64 + ni * 16 + lr;
#pragma unroll
                for (int r = 0; r < 4; ++r) {
                    int row = rb + r;
                    if (row < nvalid)
                        atomicAdd(&out[(size_t)tsh[row] * HID + col], acc[mi][ni][r] * wsh[row]);
                }
            }
        }
    }
}

// ---------------- combine: out[t] = w0*y[s0] + w1*y[s1] ----------------
__global__ __launch_bounds__(256) void combine_kernel(
    const bf16_t* __restrict__ y, const int* __restrict__ slot_of,
    const float* __restrict__ topk_w, float* __restrict__ out, int T)
{
    int t = blockIdx.x;
    int tid = threadIdx.x;
    int s0 = slot_of[t * 2], s1 = slot_of[t * 2 + 1];
    float w0 = topk_w[t * 2], w1 = topk_w[t * 2 + 1];
    const bf16x8* y0 = (const bf16x8*)(y + (size_t)s0 * HID);
    const bf16x8* y1 = (const bf16x8*)(y + (size_t)s1 * HID);
    bf16x8 v0 = y0[tid], v1 = y1[tid];
    float* op = out + (size_t)t * HID + tid * 8;
#pragma unroll
    for (int j = 0; j < 8; ++j)
        op[j] = w0 * (float)v0[j] + w1 * (float)v1[j];
}

extern "C" void kernel_launch(void* const* d_in, const int* in_sizes, int n_in,
                              void* d_out, int out_size, void* d_ws, size_t ws_size,
                              hipStream_t stream)
{
    const float* x  = (const float*)d_in[0];
    const float* gw = (const float*)d_in[1];
    const float* wg = (const float*)d_in[2];
    const float* wu = (const float*)d_in[3];
    const float* wd = (const float*)d_in[4];
    float* out = (float*)d_out;
    int T = in_sizes[0] / HID;     // 4096
    int S2 = 2 * T;

    char* base = (char*)d_ws;
    int* cnt     = (int*)base;                // 8
    int* fill    = cnt + 8;                   // 8
    int* offs    = cnt + 16;                  // 16
    int* topk_id = cnt + 32;                  // 2T
    float* topk_w = (float*)(topk_id + S2);   // 2T
    int* tok     = (int*)(topk_w + S2);       // 2T + 256 (pad for tile overrun)
    float* wslot = (float*)(tok + S2 + 256);  // 2T + 256
    int* slot_of = (int*)(wslot + S2 + 256);  // 2T
    size_t small_bytes = (size_t)(32 + 5 * S2 + 512) * 4;
    size_t hoff = (small_bytes + 255) & ~(size_t)255;
    bf16_t* h_buf = (bf16_t*)(base + hoff);
    size_t hbytes = (size_t)(S2 + 256) * FINT * sizeof(bf16_t);
    size_t yoff = (hoff + hbytes + 255) & ~(size_t)255;
    bf16_t* y_buf = (bf16_t*)(base + yoff);
    size_t ybytes = (size_t)(S2 + 256) * HID * sizeof(bf16_t);
    int useY = (yoff + ybytes <= ws_size) ? 1 : 0;

    hipMemsetAsync(base, 0, 64, stream);   // zero cnt + fill

    router_kernel<<<T, 64, 0, stream>>>(x, gw, cnt, topk_id, topk_w, T);
    offsets_kernel<<<1, 64, 0, stream>>>(cnt, offs);
    scatter_kernel<<<(T + 255) / 256, 256, 0, stream>>>(topk_id, topk_w, offs, fill, tok, wslot, slot_of, T);

    int maxTiles = (T + BM - 1) / BM;
    dim3 ggrid(NEXP * maxTiles, FINT / BN);
    gateup_kernel<<<ggrid, 256, 0, stream>>>(x, wg, wu, offs, tok, h_buf, maxTiles);

    dim3 dgrid(NEXP * maxTiles, HID / BN);
    if (!useY) hipMemsetAsync(out, 0, (size_t)out_size * sizeof(float), stream);
    down_kernel<<<dgrid, 256, 0, stream>>>(h_buf, wd, offs, tok, wslot, out, y_buf, useY, maxTiles);
    if (useY) combine_kernel<<<T, 256, 0, stream>>>(y_buf, slot_of, topk_w, out, T);
}

// Round 2
// 528.107 us; speedup vs baseline: 2.8479x; 2.8479x over previous
//
#include <hip/hip_runtime.h>
#include <hip/hip_bf16.h>

#define HID  2048
#define NEXP 8
#define FINT 1408
#define BM   128
#define BN   128
#define BK   32
#define PITCH 40   // fallback-path LDS pitch

typedef __bf16 bf16_t;
typedef __bf16 bf16x8 __attribute__((ext_vector_type(8)));
typedef float  f32x4  __attribute__((ext_vector_type(4)));

#define AS1 __attribute__((address_space(1)))
#define AS3 __attribute__((address_space(3)))

__device__ __forceinline__ void gll16(const void* g, void* l) {
    __builtin_amdgcn_global_load_lds((const AS1 void*)g, (AS3 void*)l, 16, 0, 0);
}

// ---------------- router: logits -> softmax -> top2 + counts ----------------
__global__ __launch_bounds__(64) void router_kernel(
    const float* __restrict__ x, const float* __restrict__ gw,
    int* __restrict__ cnt, int* __restrict__ topk_id, float* __restrict__ topk_w, int T)
{
    int t = blockIdx.x;
    if (t >= T) return;
    int lane = threadIdx.x;
    float acc[NEXP];
#pragma unroll
    for (int e = 0; e < NEXP; ++e) acc[e] = 0.f;
    const float* xr = x + (size_t)t * HID;
    for (int i = lane; i < HID; i += 64) {
        float xv = xr[i];
        const float4* g4 = (const float4*)(gw + (size_t)i * NEXP);
        float4 a = g4[0], b = g4[1];
        acc[0] += xv * a.x; acc[1] += xv * a.y; acc[2] += xv * a.z; acc[3] += xv * a.w;
        acc[4] += xv * b.x; acc[5] += xv * b.y; acc[6] += xv * b.z; acc[7] += xv * b.w;
    }
#pragma unroll
    for (int d = 1; d < 64; d <<= 1) {
#pragma unroll
        for (int e = 0; e < NEXP; ++e) acc[e] += __shfl_xor(acc[e], d, 64);
    }
    float mx = acc[0];
#pragma unroll
    for (int e = 1; e < NEXP; ++e) mx = fmaxf(mx, acc[e]);
    float p[NEXP]; float s = 0.f;
#pragma unroll
    for (int e = 0; e < NEXP; ++e) { p[e] = expf(acc[e] - mx); s += p[e]; }
    float inv = 1.f / s;
    int i1 = 0;
#pragma unroll
    for (int e = 1; e < NEXP; ++e) if (acc[e] > acc[i1]) i1 = e;
    int i2 = (i1 == 0) ? 1 : 0;
#pragma unroll
    for (int e = 0; e < NEXP; ++e) if (e != i1 && acc[e] > acc[i2]) i2 = e;
    if (lane == 0) {
        topk_id[t * 2 + 0] = i1; topk_id[t * 2 + 1] = i2;
        topk_w[t * 2 + 0] = p[i1] * inv; topk_w[t * 2 + 1] = p[i2] * inv;
        atomicAdd(&cnt[i1], 1); atomicAdd(&cnt[i2], 1);
    }
}

__global__ void offsets_kernel(const int* __restrict__ cnt, int* __restrict__ offs)
{
    if (threadIdx.x == 0) {
        int s = 0;
        for (int e = 0; e < NEXP; ++e) { offs[e] = s; s += cnt[e]; }
        offs[NEXP] = s;
    }
}

__global__ void scatter_kernel(
    const int* __restrict__ topk_id, const float* __restrict__ topk_w,
    const int* __restrict__ offs, int* __restrict__ fill,
    int* __restrict__ tok, float* __restrict__ wslot, int* __restrict__ slot_of, int T)
{
    int t = blockIdx.x * blockDim.x + threadIdx.x;
    if (t >= T) return;
#pragma unroll
    for (int k = 0; k < 2; ++k) {
        int e = topk_id[t * 2 + k];
        int pos = atomicAdd(&fill[e], 1);
        int slot = offs[e] + pos;
        tok[slot] = t;
        wslot[slot] = topk_w[t * 2 + k];
        slot_of[t * 2 + k] = slot;
    }
}

// ---------------- convert x fp32 -> bf16 ----------------
__global__ __launch_bounds__(256) void cvt_x_kernel(
    const float* __restrict__ in, bf16_t* __restrict__ outb, int n)
{
    int i = (blockIdx.x * 256 + threadIdx.x) * 8;
    if (i >= n) return;
    float4 v0 = *(const float4*)(in + i);
    float4 v1 = *(const float4*)(in + i + 4);
    bf16x8 o;
    o[0] = (bf16_t)v0.x; o[1] = (bf16_t)v0.y; o[2] = (bf16_t)v0.z; o[3] = (bf16_t)v0.w;
    o[4] = (bf16_t)v1.x; o[5] = (bf16_t)v1.y; o[6] = (bf16_t)v1.z; o[7] = (bf16_t)v1.w;
    *(bf16x8*)(outb + i) = o;
}

// ------- transpose-convert: in fp32 [E][R][C] -> out bf16 [E][C][R] -------
__global__ __launch_bounds__(256) void cvt_t_kernel(
    const float* __restrict__ in, bf16_t* __restrict__ outb, int R, int C)
{
    int tilesR = R >> 6, tilesC = C >> 6;
    int per = tilesR * tilesC;
    int e = blockIdx.x / per;
    int rem = blockIdx.x - e * per;
    int tr = rem / tilesC, tc = rem - tr * tilesC;
    const float* src = in + (size_t)e * R * C + (size_t)(tr * 64) * C + tc * 64;
    bf16_t* dst = outb + (size_t)e * R * C + (size_t)(tc * 64) * R + tr * 64;

    __shared__ float tile[64][65];
    int tid = threadIdx.x;
    int rr = tid >> 4;
    int cc = (tid & 15) * 4;
#pragma unroll
    for (int i = 0; i < 4; ++i) {
        float4 v = *(const float4*)(src + (size_t)(rr + i * 16) * C + cc);
        tile[rr + i * 16][cc + 0] = v.x; tile[rr + i * 16][cc + 1] = v.y;
        tile[rr + i * 16][cc + 2] = v.z; tile[rr + i * 16][cc + 3] = v.w;
    }
    __syncthreads();
    int oc = tid >> 2;
    int og = (tid & 3) * 16;
    bf16_t* dp = dst + (size_t)oc * R + og;
    bf16x8 o0, o1;
#pragma unroll
    for (int j = 0; j < 8; ++j) { o0[j] = (bf16_t)tile[og + j][oc]; o1[j] = (bf16_t)tile[og + 8 + j][oc]; }
    *(bf16x8*)dp = o0;
    *(bf16x8*)(dp + 8) = o1;
}

// ---------------- gate+up GEMM (bf16 weights, gload_lds, dbuf) ----------------
__global__ __launch_bounds__(256) void gateup2_kernel(
    const bf16_t* __restrict__ xb, const bf16_t* __restrict__ wgb, const bf16_t* __restrict__ wub,
    const int* __restrict__ offs, const int* __restrict__ tok,
    bf16_t* __restrict__ h_buf, int maxTiles)
{
    int id = blockIdx.x;
    int s = id & 7;
    int r_ = id >> 3;
    int tr = r_ % maxTiles, q = r_ / maxTiles;
    int p = q * 8 + s;                 // panel in [0, 88)
    int e = p / 11, fb = p - e * 11;
    int seg0 = offs[e];
    int nseg = offs[e + 1] - seg0;
    int rbase = tr * BM;
    if (rbase >= nseg) return;
    int nvalid = min(nseg - rbase, BM);
    int row0 = seg0 + rbase;
    int f0 = fb * BN;

    __shared__ bf16_t As[2][BM * BK];
    __shared__ bf16_t Bg[2][BN * BK];
    __shared__ bf16_t Bu[2][BN * BK];

    int tid = threadIdx.x;
    int lane = tid & 63, w = tid >> 6;
    int wm = w >> 1, wn = w & 1;
    int lr = lane & 15, lg = lane >> 4;

    // staging geometry: wave issue covers 16 rows x 32k (1 KB); per wave 2 issues per tile
    int col8 = (lane & 3) * 8;
    int r0s = (w * 2 + 0) * 16 + (lane >> 2);
    int r1s = (w * 2 + 1) * 16 + (lane >> 2);
    int tok0 = tok[row0 + min(r0s, nvalid - 1)];
    int tok1 = tok[row0 + min(r1s, nvalid - 1)];
    const bf16_t* a0 = xb + (size_t)tok0 * HID + col8;
    const bf16_t* a1 = xb + (size_t)tok1 * HID + col8;
    const bf16_t* gbase = wgb + (size_t)e * FINT * HID + (size_t)f0 * HID + col8;
    const bf16_t* ubase = wub + (size_t)e * FINT * HID + (size_t)f0 * HID + col8;
    const bf16_t* g0 = gbase + (size_t)r0s * HID;
    const bf16_t* g1 = gbase + (size_t)r1s * HID;
    const bf16_t* u0 = ubase + (size_t)r0s * HID;
    const bf16_t* u1 = ubase + (size_t)r1s * HID;

    f32x4 zero = {0.f, 0.f, 0.f, 0.f};
    f32x4 accg[4][4], accu[4][4];
#pragma unroll
    for (int i = 0; i < 4; ++i)
#pragma unroll
        for (int j = 0; j < 4; ++j) { accg[i][j] = zero; accu[i][j] = zero; }

    auto STAGE = [&](int b, int kt) {
        int k0 = kt * BK;
        gll16(a0 + k0, &As[b][(w * 2 + 0) * 512]);
        gll16(a1 + k0, &As[b][(w * 2 + 1) * 512]);
        gll16(g0 + k0, &Bg[b][(w * 2 + 0) * 512]);
        gll16(g1 + k0, &Bg[b][(w * 2 + 1) * 512]);
        gll16(u0 + k0, &Bu[b][(w * 2 + 0) * 512]);
        gll16(u1 + k0, &Bu[b][(w * 2 + 1) * 512]);
    };
    auto compute = [&](int b) {
        bf16x8 a[4];
#pragma unroll
        for (int mi = 0; mi < 4; ++mi)
            a[mi] = *(const bf16x8*)&As[b][(wm * 64 + mi * 16 + lr) * BK + lg * 8];
#pragma unroll
        for (int ni = 0; ni < 4; ++ni) {
            bf16x8 bg = *(const bf16x8*)&Bg[b][(wn * 64 + ni * 16 + lr) * BK + lg * 8];
            bf16x8 bu = *(const bf16x8*)&Bu[b][(wn * 64 + ni * 16 + lr) * BK + lg * 8];
#pragma unroll
            for (int mi = 0; mi < 4; ++mi) {
                accg[mi][ni] = __builtin_amdgcn_mfma_f32_16x16x32_bf16(a[mi], bg, accg[mi][ni], 0, 0, 0);
                accu[mi][ni] = __builtin_amdgcn_mfma_f32_16x16x32_bf16(a[mi], bu, accu[mi][ni], 0, 0, 0);
            }
        }
    };

    const int NK = HID / BK;   // 64
    STAGE(0, 0);
    __syncthreads();
    for (int kt = 0; kt < NK; ++kt) {
        int cur = kt & 1;
        if (kt + 1 < NK) STAGE(cur ^ 1, kt + 1);
        compute(cur);
        __syncthreads();
    }

#pragma unroll
    for (int mi = 0; mi < 4; ++mi) {
        int rb = wm * 64 + mi * 16 + lg * 4;
#pragma unroll
        for (int ni = 0; ni < 4; ++ni) {
            int col = f0 + wn * 64 + ni * 16 + lr;
#pragma unroll
            for (int r = 0; r < 4; ++r) {
                int row = rb + r;
                if (row < nvalid) {
                    float g = accg[mi][ni][r], u = accu[mi][ni][r];
                    float h = (g / (1.f + __expf(-g))) * u;
                    h_buf[(size_t)(row0 + row) * FINT + col] = (bf16_t)h;
                }
            }
        }
    }
}

// ---------------- down GEMM (bf16, gload_lds, dbuf) ----------------
__global__ __launch_bounds__(256) void down2_kernel(
    const bf16_t* __restrict__ h_buf, const bf16_t* __restrict__ wdb,
    const int* __restrict__ offs, const int* __restrict__ tok, const float* __restrict__ wslot,
    float* __restrict__ out, bf16_t* __restrict__ y_buf, int useY, int maxTiles)
{
    int id = blockIdx.x;
    int s = id & 7;
    int r_ = id >> 3;
    int tr = r_ % maxTiles, q = r_ / maxTiles;
    int p = q * 8 + s;                 // panel in [0, 128)
    int e = p >> 4, hb = p & 15;
    int seg0 = offs[e];
    int nseg = offs[e + 1] - seg0;
    int rbase = tr * BM;
    if (rbase >= nseg) return;
    int nvalid = min(nseg - rbase, BM);
    int row0 = seg0 + rbase;
    int h0 = hb * BN;

    __shared__ bf16_t As[2][BM * BK];
    __shared__ bf16_t Bs[2][BN * BK];
    __shared__ float wsh[BM];
    __shared__ int   tsh[BM];

    int tid = threadIdx.x;
    if (tid < BM) {
        int v = tid < nvalid;
        wsh[tid] = v ? wslot[row0 + tid] : 0.f;
        tsh[tid] = v ? tok[row0 + tid] : 0;
    }

    int lane = tid & 63, w = tid >> 6;
    int wm = w >> 1, wn = w & 1;
    int lr = lane & 15, lg = lane >> 4;

    int col8 = (lane & 3) * 8;
    int r0s = (w * 2 + 0) * 16 + (lane >> 2);
    int r1s = (w * 2 + 1) * 16 + (lane >> 2);
    const bf16_t* a0 = h_buf + (size_t)(row0 + r0s) * FINT + col8;
    const bf16_t* a1 = h_buf + (size_t)(row0 + r1s) * FINT + col8;
    const bf16_t* dbase = wdb + (size_t)e * HID * FINT + (size_t)h0 * FINT + col8;
    const bf16_t* b0 = dbase + (size_t)r0s * FINT;
    const bf16_t* b1 = dbase + (size_t)r1s * FINT;

    f32x4 zero = {0.f, 0.f, 0.f, 0.f};
    f32x4 acc[4][4];
#pragma unroll
    for (int i = 0; i < 4; ++i)
#pragma unroll
        for (int j = 0; j < 4; ++j) acc[i][j] = zero;

    auto STAGE = [&](int b, int kt) {
        int k0 = kt * BK;
        gll16(a0 + k0, &As[b][(w * 2 + 0) * 512]);
        gll16(a1 + k0, &As[b][(w * 2 + 1) * 512]);
        gll16(b0 + k0, &Bs[b][(w * 2 + 0) * 512]);
        gll16(b1 + k0, &Bs[b][(w * 2 + 1) * 512]);
    };
    auto compute = [&](int b) {
        bf16x8 a[4];
#pragma unroll
        for (int mi = 0; mi < 4; ++mi)
            a[mi] = *(const bf16x8*)&As[b][(wm * 64 + mi * 16 + lr) * BK + lg * 8];
#pragma unroll
        for (int ni = 0; ni < 4; ++ni) {
            bf16x8 bb = *(const bf16x8*)&Bs[b][(wn * 64 + ni * 16 + lr) * BK + lg * 8];
#pragma unroll
            for (int mi = 0; mi < 4; ++mi)
                acc[mi][ni] = __builtin_amdgcn_mfma_f32_16x16x32_bf16(a[mi], bb, acc[mi][ni], 0, 0, 0);
        }
    };

    const int NK = FINT / BK;  // 44
    STAGE(0, 0);
    __syncthreads();
    for (int kt = 0; kt < NK; ++kt) {
        int cur = kt & 1;
        if (kt + 1 < NK) STAGE(cur ^ 1, kt + 1);
        compute(cur);
        __syncthreads();
    }

    if (useY) {
#pragma unroll
        for (int mi = 0; mi < 4; ++mi) {
            int rb = wm * 64 + mi * 16 + lg * 4;
#pragma unroll
            for (int ni = 0; ni < 4; ++ni) {
                int col = h0 + wn * 64 + ni * 16 + lr;
#pragma unroll
                for (int r = 0; r < 4; ++r) {
                    int row = rb + r;
                    if (row < nvalid)
                        y_buf[(size_t)(row0 + row) * HID + col] = (bf16_t)acc[mi][ni][r];
                }
            }
        }
    } else {
#pragma unroll
        for (int mi = 0; mi < 4; ++mi) {
            int rb = wm * 64 + mi * 16 + lg * 4;
#pragma unroll
            for (int ni = 0; ni < 4; ++ni) {
                int col = h0 + wn * 64 + ni * 16 + lr;
#pragma unroll
                for (int r = 0; r < 4; ++r) {
                    int row = rb + r;
                    if (row < nvalid)
                        atomicAdd(&out[(size_t)tsh[row] * HID + col], acc[mi][ni][r] * wsh[row]);
                }
            }
        }
    }
}

// ---------------- combine: out[t] = w0*y[s0] + w1*y[s1] ----------------
__global__ __launch_bounds__(256) void combine_kernel(
    const bf16_t* __restrict__ y, const int* __restrict__ slot_of,
    const float* __restrict__ topk_w, float* __restrict__ out, int T)
{
    int t = blockIdx.x;
    int tid = threadIdx.x;
    int s0 = slot_of[t * 2], s1 = slot_of[t * 2 + 1];
    float w0 = topk_w[t * 2], w1 = topk_w[t * 2 + 1];
    const bf16x8* y0 = (const bf16x8*)(y + (size_t)s0 * HID);
    const bf16x8* y1 = (const bf16x8*)(y + (size_t)s1 * HID);
    bf16x8 v0 = y0[tid], v1 = y1[tid];
    float* op = out + (size_t)t * HID + tid * 8;
#pragma unroll
    for (int j = 0; j < 8; ++j)
        op[j] = w0 * (float)v0[j] + w1 * (float)v1[j];
}

// ================= fallback (round-1) GEMMs: fp32 weights, reg staging ==========
__global__ __launch_bounds__(256) void gateup_fb_kernel(
    const float* __restrict__ x, const float* __restrict__ wg, const float* __restrict__ wu,
    const int* __restrict__ offs, const int* __restrict__ tok,
    bf16_t* __restrict__ h_buf, int maxTiles)
{
    int e = blockIdx.x / maxTiles;
    int tr = blockIdx.x - e * maxTiles;
    int seg0 = offs[e];
    int nseg = offs[e + 1] - seg0;
    int rbase = tr * BM;
    if (rbase >= nseg) return;
    int nvalid = nseg - rbase; if (nvalid > BM) nvalid = BM;
    int row0 = seg0 + rbase;
    int f0 = blockIdx.y * BN;

    __shared__ bf16_t As[BM * PITCH];
    __shared__ bf16_t Bgs[BN * PITCH];
    __shared__ bf16_t Bus[BN * PITCH];

    int tid = threadIdx.x;
    int lane = tid & 63, wid = tid >> 6;
    int wm = wid >> 1, wn = wid & 1;
    int lr = lane & 15, lg = lane >> 4;

    int a_r = tid >> 1;
    int a_k = (tid & 1) * 16;
    int tkn = (a_r < nvalid) ? tok[row0 + a_r] : 0;
    const float* aptr = x + (size_t)tkn * HID + a_k;

    int b_n = tid & (BN - 1);
    int b_k = (tid >> 7) * 16;
    const float* gptr = wg + (size_t)e * HID * FINT + (size_t)b_k * FINT + f0 + b_n;
    const float* uptr = wu + (size_t)e * HID * FINT + (size_t)b_k * FINT + f0 + b_n;

    f32x4 zero = {0.f, 0.f, 0.f, 0.f};
    f32x4 accg[4][4], accu[4][4];
#pragma unroll
    for (int i = 0; i < 4; ++i)
#pragma unroll
        for (int j = 0; j < 4; ++j) { accg[i][j] = zero; accu[i][j] = zero; }

    float ar[16], bgr[16], bur[16];
    auto load_stage = [&](int kt) {
        const float4* a4 = (const float4*)(aptr + (size_t)kt * BK);
#pragma unroll
        for (int i = 0; i < 4; ++i) {
            float4 v = a4[i];
            ar[i * 4 + 0] = v.x; ar[i * 4 + 1] = v.y; ar[i * 4 + 2] = v.z; ar[i * 4 + 3] = v.w;
        }
        const float* gp = gptr + (size_t)kt * BK * FINT;
        const float* up = uptr + (size_t)kt * BK * FINT;
#pragma unroll
        for (int i = 0; i < 16; ++i) { bgr[i] = gp[(size_t)i * FINT]; bur[i] = up[(size_t)i * FINT]; }
    };
    auto write_stage = [&]() {
        bf16x8 w0, w1;
#pragma unroll
        for (int j = 0; j < 8; ++j) { w0[j] = (bf16_t)ar[j]; w1[j] = (bf16_t)ar[8 + j]; }
        *(bf16x8*)&As[a_r * PITCH + a_k] = w0;
        *(bf16x8*)&As[a_r * PITCH + a_k + 8] = w1;
#pragma unroll
        for (int j = 0; j < 8; ++j) { w0[j] = (bf16_t)bgr[j]; w1[j] = (bf16_t)bgr[8 + j]; }
        *(bf16x8*)&Bgs[b_n * PITCH + b_k] = w0;
        *(bf16x8*)&Bgs[b_n * PITCH + b_k + 8] = w1;
#pragma unroll
        for (int j = 0; j < 8; ++j) { w0[j] = (bf16_t)bur[j]; w1[j] = (bf16_t)bur[8 + j]; }
        *(bf16x8*)&Bus[b_n * PITCH + b_k] = w0;
        *(bf16x8*)&Bus[b_n * PITCH + b_k + 8] = w1;
    };
    auto compute = [&]() {
        bf16x8 a[4];
#pragma unroll
        for (int mi = 0; mi < 4; ++mi)
            a[mi] = *(const bf16x8*)&As[(wm * 64 + mi * 16 + lr) * PITCH + lg * 8];
#pragma unroll
        for (int ni = 0; ni < 4; ++ni) {
            bf16x8 bg = *(const bf16x8*)&Bgs[(wn * 64 + ni * 16 + lr) * PITCH + lg * 8];
            bf16x8 bu = *(const bf16x8*)&Bus[(wn * 64 + ni * 16 + lr) * PITCH + lg * 8];
#pragma unroll
            for (int mi = 0; mi < 4; ++mi) {
                accg[mi][ni] = __builtin_amdgcn_mfma_f32_16x16x32_bf16(a[mi], bg, accg[mi][ni], 0, 0, 0);
                accu[mi][ni] = __builtin_amdgcn_mfma_f32_16x16x32_bf16(a[mi], bu, accu[mi][ni], 0, 0, 0);
            }
        }
    };

    const int NK = HID / BK;
    load_stage(0);
    for (int kt = 0; kt < NK; ++kt) {
        __syncthreads();
        write_stage();
        __syncthreads();
        if (kt + 1 < NK) load_stage(kt + 1);
        compute();
    }

#pragma unroll
    for (int mi = 0; mi < 4; ++mi) {
        int rb = wm * 64 + mi * 16 + lg * 4;
#pragma unroll
        for (int ni = 0; ni < 4; ++ni) {
            int col = f0 + wn * 64 + ni * 16 + lr;
#pragma unroll
            for (int r = 0; r < 4; ++r) {
                int row = rb + r;
                if (row < nvalid) {
                    float g = accg[mi][ni][r], u = accu[mi][ni][r];
                    float h = (g / (1.f + __expf(-g))) * u;
                    h_buf[(size_t)(row0 + row) * FINT + col] = (bf16_t)h;
                }
            }
        }
    }
}

__global__ __launch_bounds__(256) void down_fb_kernel(
    const bf16_t* __restrict__ h_buf, const float* __restrict__ wd,
    const int* __restrict__ offs, const int* __restrict__ tok, const float* __restrict__ wslot,
    float* __restrict__ out, bf16_t* __restrict__ y_buf, int useY, int maxTiles)
{
    int e = blockIdx.x / maxTiles;
    int tr = blockIdx.x - e * maxTiles;
    int seg0 = offs[e];
    int nseg = offs[e + 1] - seg0;
    int rbase = tr * BM;
    if (rbase >= nseg) return;
    int nvalid = nseg - rbase; if (nvalid > BM) nvalid = BM;
    int row0 = seg0 + rbase;
    int h0 = blockIdx.y * BN;

    __shared__ bf16_t As[BM * PITCH];
    __shared__ bf16_t Bs[BN * PITCH];
    __shared__ float wsh[BM];
    __shared__ int   tsh[BM];

    int tid = threadIdx.x;
    if (tid < BM) {
        int v = tid < nvalid;
        wsh[tid] = v ? wslot[row0 + tid] : 0.f;
        tsh[tid] = v ? tok[row0 + tid] : 0;
    }

    int lane = tid & 63, wid = tid >> 6;
    int wm = wid >> 1, wn = wid & 1;
    int lr = lane & 15, lg = lane >> 4;

    int a_r = tid >> 1;
    int a_k = (tid & 1) * 16;
    const bf16_t* aptr = h_buf + (size_t)(row0 + a_r) * FINT + a_k;

    int b_n = tid & (BN - 1);
    int b_k = (tid >> 7) * 16;
    const float* dptr = wd + (size_t)e * FINT * HID + (size_t)b_k * HID + h0 + b_n;

    f32x4 zero = {0.f, 0.f, 0.f, 0.f};
    f32x4 acc[4][4];
#pragma unroll
    for (int i = 0; i < 4; ++i)
#pragma unroll
        for (int j = 0; j < 4; ++j) acc[i][j] = zero;

    bf16x8 ar0, ar1; float br[16];
    auto load_stage = [&](int kt) {
        const bf16x8* a8 = (const bf16x8*)(aptr + (size_t)kt * BK);
        ar0 = a8[0]; ar1 = a8[1];
        const float* dp = dptr + (size_t)kt * BK * HID;
#pragma unroll
        for (int i = 0; i < 16; ++i) br[i] = dp[(size_t)i * HID];
    };
    auto write_stage = [&]() {
        *(bf16x8*)&As[a_r * PITCH + a_k] = ar0;
        *(bf16x8*)&As[a_r * PITCH + a_k + 8] = ar1;
        bf16x8 w0, w1;
#pragma unroll
        for (int j = 0; j < 8; ++j) { w0[j] = (bf16_t)br[j]; w1[j] = (bf16_t)br[8 + j]; }
        *(bf16x8*)&Bs[b_n * PITCH + b_k] = w0;
        *(bf16x8*)&Bs[b_n * PITCH + b_k + 8] = w1;
    };
    auto compute = [&]() {
        bf16x8 a[4];
#pragma unroll
        for (int mi = 0; mi < 4; ++mi)
            a[mi] = *(const bf16x8*)&As[(wm * 64 + mi * 16 + lr) * PITCH + lg * 8];
#pragma unroll
        for (int ni = 0; ni < 4; ++ni) {
            bf16x8 b = *(const bf16x8*)&Bs[(wn * 64 + ni * 16 + lr) * PITCH + lg * 8];
#pragma unroll
            for (int mi = 0; mi < 4; ++mi)
                acc[mi][ni] = __builtin_amdgcn_mfma_f32_16x16x32_bf16(a[mi], b, acc[mi][ni], 0, 0, 0);
        }
    };

    const int NK = FINT / BK;
    load_stage(0);
    for (int kt = 0; kt < NK; ++kt) {
        __syncthreads();
        write_stage();
        __syncthreads();
        if (kt + 1 < NK) load_stage(kt + 1);
        compute();
    }

    if (useY) {
#pragma unroll
        for (int mi = 0; mi < 4; ++mi) {
            int rb = wm * 64 + mi * 16 + lg * 4;
#pragma unroll
            for (int ni = 0; ni < 4; ++ni) {
                int col = h0 + wn * 64 + ni * 16 + lr;
#pragma unroll
                for (int r = 0; r < 4; ++r) {
                    int row = rb + r;
                    if (row < nvalid)
                        y_buf[(size_t)(row0 + row) * HID + col] = (bf16_t)acc[mi][ni][r];
                }
            }
        }
    } else {
#pragma unroll
        for (int mi = 0; mi < 4; ++mi) {
            int rb = wm * 64 + mi * 16 + lg * 4;
#pragma unroll
            for (int ni = 0; ni < 4; ++ni) {
                int col = h0 + wn * 64 + ni * 16 + lr;
#pragma unroll
                for (int r = 0; r < 4; ++r) {
                    int row = rb + r;
                    if (row < nvalid)
                        atomicAdd(&out[(size_t)tsh[row] * HID + col], acc[mi][ni][r] * wsh[row]);
                }
            }
        }
    }
}

extern "C" void kernel_launch(void* const* d_in, const int* in_sizes, int n_in,
                              void* d_out, int out_size, void* d_ws, size_t ws_size,
                              hipStream_t stream)
{
    const float* x  = (const float*)d_in[0];
    const float* gw = (const float*)d_in[1];
    const float* wg = (const float*)d_in[2];
    const float* wu = (const float*)d_in[3];
    const float* wd = (const float*)d_in[4];
    float* out = (float*)d_out;
    int T = in_sizes[0] / HID;     // 4096
    int S2 = 2 * T;
    int maxTiles = (T + BM - 1) / BM;   // 32

    char* base = (char*)d_ws;
    int* cnt     = (int*)base;
    int* fill    = cnt + 8;
    int* offs    = cnt + 16;
    int* topk_id = cnt + 32;
    float* topk_w = (float*)(topk_id + S2);
    int* tok     = (int*)(topk_w + S2);
    float* wslot = (float*)(tok + S2 + 256);
    int* slot_of = (int*)(wslot + S2 + 256);
    size_t small_end = (size_t)((char*)(slot_of + S2) - base);
    size_t cur = (small_end + 255) & ~(size_t)255;
    auto take = [&](size_t bytes) -> size_t {
        size_t o = cur; cur += bytes; cur = (cur + 255) & ~(size_t)255; return o;
    };
    size_t wbytes = (size_t)NEXP * HID * FINT * 2;
    size_t o_xb  = take((size_t)T * HID * 2);
    size_t o_wgb = take(wbytes);
    size_t o_wub = take(wbytes);
    size_t o_wdb = take(wbytes);
    size_t o_h   = take((size_t)(S2 + 256) * FINT * 2);
    size_t needA = cur;
    size_t o_y   = take((size_t)(S2 + 256) * HID * 2);
    size_t needY = cur;

    int useNew = (ws_size >= needA);
    int useY   = (ws_size >= needY);

    hipMemsetAsync(base, 0, 64, stream);   // cnt + fill
    router_kernel<<<T, 64, 0, stream>>>(x, gw, cnt, topk_id, topk_w, T);
    offsets_kernel<<<1, 64, 0, stream>>>(cnt, offs);
    scatter_kernel<<<(T + 255) / 256, 256, 0, stream>>>(topk_id, topk_w, offs, fill, tok, wslot, slot_of, T);

    if (useNew) {
        bf16_t* xb  = (bf16_t*)(base + o_xb);
        bf16_t* wgb = (bf16_t*)(base + o_wgb);
        bf16_t* wub = (bf16_t*)(base + o_wub);
        bf16_t* wdb = (bf16_t*)(base + o_wdb);
        bf16_t* h_buf = (bf16_t*)(base + o_h);
        bf16_t* y_buf = (bf16_t*)(base + o_y);

        int nx = T * HID;
        cvt_x_kernel<<<nx / 2048, 256, 0, stream>>>(x, xb, nx);
        // wg, wu: [E][H][F] -> [E][F][H]
        int gridW = NEXP * (HID / 64) * (FINT / 64);   // 5632
        cvt_t_kernel<<<gridW, 256, 0, stream>>>(wg, wgb, HID, FINT);
        cvt_t_kernel<<<gridW, 256, 0, stream>>>(wu, wub, HID, FINT);
        // wd: [E][F][H] -> [E][H][F]
        cvt_t_kernel<<<gridW, 256, 0, stream>>>(wd, wdb, FINT, HID);

        int ggrid = NEXP * (FINT / BN) * maxTiles;     // 2816
        gateup2_kernel<<<ggrid, 256, 0, stream>>>(xb, wgb, wub, offs, tok, h_buf, maxTiles);

        int dgrid = NEXP * (HID / BN) * maxTiles;      // 4096
        if (!useY) hipMemsetAsync(out, 0, (size_t)out_size * sizeof(float), stream);
        down2_kernel<<<dgrid, 256, 0, stream>>>(h_buf, wdb, offs, tok, wslot, out, y_buf, useY, maxTiles);
        if (useY) combine_kernel<<<T, 256, 0, stream>>>(y_buf, slot_of, topk_w, out, T);
    } else {
        // fallback: round-1 layout (h, y right after small block)
        size_t fcur = (small_end + 255) & ~(size_t)255;
        bf16_t* h_buf = (bf16_t*)(base + fcur);
        size_t hbytes = (size_t)(S2 + 256) * FINT * 2;
        size_t yoff = (fcur + hbytes + 255) & ~(size_t)255;
        bf16_t* y_buf = (bf16_t*)(base + yoff);
        size_t ybytes = (size_t)(S2 + 256) * HID * 2;
        int useYf = (yoff + ybytes <= ws_size) ? 1 : 0;

        dim3 ggrid(NEXP * maxTiles, FINT / BN);
        gateup_fb_kernel<<<ggrid, 256, 0, stream>>>(x, wg, wu, offs, tok, h_buf, maxTiles);
        dim3 dgrid(NEXP * maxTiles, HID / BN);
        if (!useYf) hipMemsetAsync(out, 0, (size_t)out_size * sizeof(float), stream);
        down_fb_kernel<<<dgrid, 256, 0, stream>>>(h_buf, wd, offs, tok, wslot, out, y_buf, useYf, maxTiles);
        if (useYf) combine_kernel<<<T, 256, 0, stream>>>(y_buf, slot_of, topk_w, out, T);
    }
}

// Round 3
// 521.542 us; speedup vs baseline: 2.8838x; 1.0126x over previous
//
#include <hip/hip_runtime.h>
#include <hip/hip_bf16.h>

#define HID  2048
#define NEXP 8
#define FINT 1408
#define BM   128
#define BN   128
#define BK   32
#define PITCH 40   // fallback-path LDS pitch

typedef __bf16 bf16_t;
typedef __bf16 bf16x8 __attribute__((ext_vector_type(8)));
typedef float  f32x4  __attribute__((ext_vector_type(4)));

#define AS1 __attribute__((address_space(1)))
#define AS3 __attribute__((address_space(3)))

__device__ __forceinline__ void gll16(const void* g, void* l) {
    __builtin_amdgcn_global_load_lds((const AS1 void*)g, (AS3 void*)l, 16, 0, 0);
}

// ---------------- router: logits -> softmax -> top2 + counts (+ x->bf16) ----------------
__global__ __launch_bounds__(64) void router_kernel(
    const float* __restrict__ x, const float* __restrict__ gw,
    int* __restrict__ cnt, int* __restrict__ topk_id, float* __restrict__ topk_w,
    bf16_t* __restrict__ xb, int T)
{
    int t = blockIdx.x;
    if (t >= T) return;
    int lane = threadIdx.x;
    float acc[NEXP];
#pragma unroll
    for (int e = 0; e < NEXP; ++e) acc[e] = 0.f;
    const float* xr = x + (size_t)t * HID;
    bf16_t* xo = xb ? xb + (size_t)t * HID : nullptr;
    for (int i = lane; i < HID; i += 64) {
        float xv = xr[i];
        if (xo) xo[i] = (bf16_t)xv;
        const float4* g4 = (const float4*)(gw + (size_t)i * NEXP);
        float4 a = g4[0], b = g4[1];
        acc[0] += xv * a.x; acc[1] += xv * a.y; acc[2] += xv * a.z; acc[3] += xv * a.w;
        acc[4] += xv * b.x; acc[5] += xv * b.y; acc[6] += xv * b.z; acc[7] += xv * b.w;
    }
#pragma unroll
    for (int d = 1; d < 64; d <<= 1) {
#pragma unroll
        for (int e = 0; e < NEXP; ++e) acc[e] += __shfl_xor(acc[e], d, 64);
    }
    float mx = acc[0];
#pragma unroll
    for (int e = 1; e < NEXP; ++e) mx = fmaxf(mx, acc[e]);
    float p[NEXP]; float s = 0.f;
#pragma unroll
    for (int e = 0; e < NEXP; ++e) { p[e] = expf(acc[e] - mx); s += p[e]; }
    float inv = 1.f / s;
    int i1 = 0;
#pragma unroll
    for (int e = 1; e < NEXP; ++e) if (acc[e] > acc[i1]) i1 = e;
    int i2 = (i1 == 0) ? 1 : 0;
#pragma unroll
    for (int e = 0; e < NEXP; ++e) if (e != i1 && acc[e] > acc[i2]) i2 = e;
    if (lane == 0) {
        topk_id[t * 2 + 0] = i1; topk_id[t * 2 + 1] = i2;
        topk_w[t * 2 + 0] = p[i1] * inv; topk_w[t * 2 + 1] = p[i2] * inv;
        atomicAdd(&cnt[i1], 1); atomicAdd(&cnt[i2], 1);
    }
}

__global__ void offsets_kernel(const int* __restrict__ cnt, int* __restrict__ offs)
{
    if (threadIdx.x == 0) {
        int s = 0;
        for (int e = 0; e < NEXP; ++e) { offs[e] = s; s += cnt[e]; }
        offs[NEXP] = s;
    }
}

__global__ void scatter_kernel(
    const int* __restrict__ topk_id, const float* __restrict__ topk_w,
    const int* __restrict__ offs, int* __restrict__ fill,
    int* __restrict__ tok, float* __restrict__ wslot, int* __restrict__ slot_of, int T)
{
    int t = blockIdx.x * blockDim.x + threadIdx.x;
    if (t >= T) return;
#pragma unroll
    for (int k = 0; k < 2; ++k) {
        int e = topk_id[t * 2 + k];
        int pos = atomicAdd(&fill[e], 1);
        int slot = offs[e] + pos;
        tok[slot] = t;
        wslot[slot] = topk_w[t * 2 + k];
        slot_of[t * 2 + k] = slot;
    }
}

// ------- transpose-convert: in fp32 [E][R][C] -> out bf16 [E][C][R] -------
__global__ __launch_bounds__(256) void cvt_t_kernel(
    const float* __restrict__ in, bf16_t* __restrict__ outb, int R, int C)
{
    int tilesR = R >> 6, tilesC = C >> 6;
    int per = tilesR * tilesC;
    int e = blockIdx.x / per;
    int rem = blockIdx.x - e * per;
    int tr = rem / tilesC, tc = rem - tr * tilesC;
    const float* src = in + (size_t)e * R * C + (size_t)(tr * 64) * C + tc * 64;
    bf16_t* dst = outb + (size_t)e * R * C + (size_t)(tc * 64) * R + tr * 64;

    __shared__ float tile[64][65];
    int tid = threadIdx.x;
    int rr = tid >> 4;
    int cc = (tid & 15) * 4;
#pragma unroll
    for (int i = 0; i < 4; ++i) {
        float4 v = *(const float4*)(src + (size_t)(rr + i * 16) * C + cc);
        tile[rr + i * 16][cc + 0] = v.x; tile[rr + i * 16][cc + 1] = v.y;
        tile[rr + i * 16][cc + 2] = v.z; tile[rr + i * 16][cc + 3] = v.w;
    }
    __syncthreads();
    int oc = tid >> 2;
    int og = (tid & 3) * 16;
    bf16_t* dp = dst + (size_t)oc * R + og;
    bf16x8 o0, o1;
#pragma unroll
    for (int j = 0; j < 8; ++j) { o0[j] = (bf16_t)tile[og + j][oc]; o1[j] = (bf16_t)tile[og + 8 + j][oc]; }
    *(bf16x8*)dp = o0;
    *(bf16x8*)(dp + 8) = o1;
}

// ---------------- gate+up GEMM (bf16, gload_lds, dbuf, XOR-swizzled LDS) ----------------
__global__ __launch_bounds__(256) void gateup2_kernel(
    const bf16_t* __restrict__ xb, const bf16_t* __restrict__ wgb, const bf16_t* __restrict__ wub,
    const int* __restrict__ offs, const int* __restrict__ tok,
    bf16_t* __restrict__ h_buf, int maxTiles)
{
    int id = blockIdx.x;
    int s = id & 7;
    int r_ = id >> 3;
    int tr = r_ % maxTiles, q = r_ / maxTiles;
    int p = q * 8 + s;                 // panel in [0, 88)
    int e = p / 11, fb = p - e * 11;
    int seg0 = offs[e];
    int nseg = offs[e + 1] - seg0;
    int rbase = tr * BM;
    if (rbase >= nseg) return;
    int nvalid = min(nseg - rbase, BM);
    int row0 = seg0 + rbase;
    int f0 = fb * BN;

    __shared__ bf16_t As[2][BM * BK];
    __shared__ bf16_t Bg[2][BN * BK];
    __shared__ bf16_t Bu[2][BN * BK];

    int tid = threadIdx.x;
    int lane = tid & 63, w = tid >> 6;
    int wm = w >> 1, wn = w & 1;
    int lr = lane & 15, lg = lane >> 4;

    // staging: linear LDS dest (base + lane*16); SOURCE k-slot pre-swizzled so that
    // read-side swizzle slot' = lg ^ ((lr>>1)&3) sees the right data (rule #21).
    int sw8 = ((lane & 3) ^ ((lane >> 3) & 3)) * 8;   // swizzled k-elem offset in [0,32)
    int r0s = (w * 2 + 0) * 16 + (lane >> 2);
    int r1s = (w * 2 + 1) * 16 + (lane >> 2);
    int tok0 = tok[row0 + min(r0s, nvalid - 1)];
    int tok1 = tok[row0 + min(r1s, nvalid - 1)];
    const bf16_t* a0 = xb + (size_t)tok0 * HID + sw8;
    const bf16_t* a1 = xb + (size_t)tok1 * HID + sw8;
    const bf16_t* gbase = wgb + (size_t)e * FINT * HID + (size_t)f0 * HID + sw8;
    const bf16_t* ubase = wub + (size_t)e * FINT * HID + (size_t)f0 * HID + sw8;
    const bf16_t* g0 = gbase + (size_t)r0s * HID;
    const bf16_t* g1 = gbase + (size_t)r1s * HID;
    const bf16_t* u0 = ubase + (size_t)r0s * HID;
    const bf16_t* u1 = ubase + (size_t)r1s * HID;

    f32x4 zero = {0.f, 0.f, 0.f, 0.f};
    f32x4 accg[4][4], accu[4][4];
#pragma unroll
    for (int i = 0; i < 4; ++i)
#pragma unroll
        for (int j = 0; j < 4; ++j) { accg[i][j] = zero; accu[i][j] = zero; }

    auto STAGE = [&](int b, int kt) {
        int k0 = kt * BK;
        gll16(a0 + k0, &As[b][(w * 2 + 0) * 512]);
        gll16(a1 + k0, &As[b][(w * 2 + 1) * 512]);
        gll16(g0 + k0, &Bg[b][(w * 2 + 0) * 512]);
        gll16(g1 + k0, &Bg[b][(w * 2 + 1) * 512]);
        gll16(u0 + k0, &Bu[b][(w * 2 + 0) * 512]);
        gll16(u1 + k0, &Bu[b][(w * 2 + 1) * 512]);
    };
    int ksw = (lg ^ ((lr >> 1) & 3)) * 8;             // read-side swizzled k-offset
    auto compute = [&](int b) {
        bf16x8 a[4];
#pragma unroll
        for (int mi = 0; mi < 4; ++mi)
            a[mi] = *(const bf16x8*)&As[b][(wm * 64 + mi * 16 + lr) * BK + ksw];
#pragma unroll
        for (int ni = 0; ni < 4; ++ni) {
            bf16x8 bg = *(const bf16x8*)&Bg[b][(wn * 64 + ni * 16 + lr) * BK + ksw];
            bf16x8 bu = *(const bf16x8*)&Bu[b][(wn * 64 + ni * 16 + lr) * BK + ksw];
#pragma unroll
            for (int mi = 0; mi < 4; ++mi) {
                accg[mi][ni] = __builtin_amdgcn_mfma_f32_16x16x32_bf16(a[mi], bg, accg[mi][ni], 0, 0, 0);
                accu[mi][ni] = __builtin_amdgcn_mfma_f32_16x16x32_bf16(a[mi], bu, accu[mi][ni], 0, 0, 0);
            }
        }
    };

    const int NK = HID / BK;   // 64
    STAGE(0, 0);
    __syncthreads();
    for (int kt = 0; kt < NK; ++kt) {
        int cur = kt & 1;
        if (kt + 1 < NK) STAGE(cur ^ 1, kt + 1);
        compute(cur);
        __syncthreads();
    }

#pragma unroll
    for (int mi = 0; mi < 4; ++mi) {
        int rb = wm * 64 + mi * 16 + lg * 4;
#pragma unroll
        for (int ni = 0; ni < 4; ++ni) {
            int col = f0 + wn * 64 + ni * 16 + lr;
#pragma unroll
            for (int r = 0; r < 4; ++r) {
                int row = rb + r;
                if (row < nvalid) {
                    float g = accg[mi][ni][r], u = accu[mi][ni][r];
                    float h = (g / (1.f + __expf(-g))) * u;
                    h_buf[(size_t)(row0 + row) * FINT + col] = (bf16_t)h;
                }
            }
        }
    }
}

// ---------------- down GEMM (bf16, gload_lds, dbuf, XOR-swizzled LDS) ----------------
__global__ __launch_bounds__(256) void down2_kernel(
    const bf16_t* __restrict__ h_buf, const bf16_t* __restrict__ wdb,
    const int* __restrict__ offs, const int* __restrict__ tok, const float* __restrict__ wslot,
    float* __restrict__ out, bf16_t* __restrict__ y_buf, int useY, int maxTiles)
{
    int id = blockIdx.x;
    int s = id & 7;
    int r_ = id >> 3;
    int tr = r_ % maxTiles, q = r_ / maxTiles;
    int p = q * 8 + s;                 // panel in [0, 128)
    int e = p >> 4, hb = p & 15;
    int seg0 = offs[e];
    int nseg = offs[e + 1] - seg0;
    int rbase = tr * BM;
    if (rbase >= nseg) return;
    int nvalid = min(nseg - rbase, BM);
    int row0 = seg0 + rbase;
    int h0 = hb * BN;

    __shared__ bf16_t As[2][BM * BK];
    __shared__ bf16_t Bs[2][BN * BK];
    __shared__ float wsh[BM];
    __shared__ int   tsh[BM];

    int tid = threadIdx.x;
    if (tid < BM) {
        int v = tid < nvalid;
        wsh[tid] = v ? wslot[row0 + tid] : 0.f;
        tsh[tid] = v ? tok[row0 + tid] : 0;
    }

    int lane = tid & 63, w = tid >> 6;
    int wm = w >> 1, wn = w & 1;
    int lr = lane & 15, lg = lane >> 4;

    int sw8 = ((lane & 3) ^ ((lane >> 3) & 3)) * 8;
    int r0s = (w * 2 + 0) * 16 + (lane >> 2);
    int r1s = (w * 2 + 1) * 16 + (lane >> 2);
    const bf16_t* a0 = h_buf + (size_t)(row0 + r0s) * FINT + sw8;
    const bf16_t* a1 = h_buf + (size_t)(row0 + r1s) * FINT + sw8;
    const bf16_t* dbase = wdb + (size_t)e * HID * FINT + (size_t)h0 * FINT + sw8;
    const bf16_t* b0 = dbase + (size_t)r0s * FINT;
    const bf16_t* b1 = dbase + (size_t)r1s * FINT;

    f32x4 zero = {0.f, 0.f, 0.f, 0.f};
    f32x4 acc[4][4];
#pragma unroll
    for (int i = 0; i < 4; ++i)
#pragma unroll
        for (int j = 0; j < 4; ++j) acc[i][j] = zero;

    auto STAGE = [&](int b, int kt) {
        int k0 = kt * BK;
        gll16(a0 + k0, &As[b][(w * 2 + 0) * 512]);
        gll16(a1 + k0, &As[b][(w * 2 + 1) * 512]);
        gll16(b0 + k0, &Bs[b][(w * 2 + 0) * 512]);
        gll16(b1 + k0, &Bs[b][(w * 2 + 1) * 512]);
    };
    int ksw = (lg ^ ((lr >> 1) & 3)) * 8;
    auto compute = [&](int b) {
        bf16x8 a[4];
#pragma unroll
        for (int mi = 0; mi < 4; ++mi)
            a[mi] = *(const bf16x8*)&As[b][(wm * 64 + mi * 16 + lr) * BK + ksw];
#pragma unroll
        for (int ni = 0; ni < 4; ++ni) {
            bf16x8 bb = *(const bf16x8*)&Bs[b][(wn * 64 + ni * 16 + lr) * BK + ksw];
#pragma unroll
            for (int mi = 0; mi < 4; ++mi)
                acc[mi][ni] = __builtin_amdgcn_mfma_f32_16x16x32_bf16(a[mi], bb, acc[mi][ni], 0, 0, 0);
        }
    };

    const int NK = FINT / BK;  // 44
    STAGE(0, 0);
    __syncthreads();
    for (int kt = 0; kt < NK; ++kt) {
        int cur = kt & 1;
        if (kt + 1 < NK) STAGE(cur ^ 1, kt + 1);
        compute(cur);
        __syncthreads();
    }

    if (useY) {
#pragma unroll
        for (int mi = 0; mi < 4; ++mi) {
            int rb = wm * 64 + mi * 16 + lg * 4;
#pragma unroll
            for (int ni = 0; ni < 4; ++ni) {
                int col = h0 + wn * 64 + ni * 16 + lr;
#pragma unroll
                for (int r = 0; r < 4; ++r) {
                    int row = rb + r;
                    if (row < nvalid)
                        y_buf[(size_t)(row0 + row) * HID + col] = (bf16_t)acc[mi][ni][r];
                }
            }
        }
    } else {
#pragma unroll
        for (int mi = 0; mi < 4; ++mi) {
            int rb = wm * 64 + mi * 16 + lg * 4;
#pragma unroll
            for (int ni = 0; ni < 4; ++ni) {
                int col = h0 + wn * 64 + ni * 16 + lr;
#pragma unroll
                for (int r = 0; r < 4; ++r) {
                    int row = rb + r;
                    if (row < nvalid)
                        atomicAdd(&out[(size_t)tsh[row] * HID + col], acc[mi][ni][r] * wsh[row]);
                }
            }
        }
    }
}

// ---------------- combine: out[t] = w0*y[s0] + w1*y[s1] ----------------
__global__ __launch_bounds__(256) void combine_kernel(
    const bf16_t* __restrict__ y, const int* __restrict__ slot_of,
    const float* __restrict__ topk_w, float* __restrict__ out, int T)
{
    int t = blockIdx.x;
    int tid = threadIdx.x;
    int s0 = slot_of[t * 2], s1 = slot_of[t * 2 + 1];
    float w0 = topk_w[t * 2], w1 = topk_w[t * 2 + 1];
    const bf16x8* y0 = (const bf16x8*)(y + (size_t)s0 * HID);
    const bf16x8* y1 = (const bf16x8*)(y + (size_t)s1 * HID);
    bf16x8 v0 = y0[tid], v1 = y1[tid];
    float* op = out + (size_t)t * HID + tid * 8;
#pragma unroll
    for (int j = 0; j < 8; ++j)
        op[j] = w0 * (float)v0[j] + w1 * (float)v1[j];
}

// ================= fallback (round-1) GEMMs: fp32 weights, reg staging ==========
__global__ __launch_bounds__(256) void gateup_fb_kernel(
    const float* __restrict__ x, const float* __restrict__ wg, const float* __restrict__ wu,
    const int* __restrict__ offs, const int* __restrict__ tok,
    bf16_t* __restrict__ h_buf, int maxTiles)
{
    int e = blockIdx.x / maxTiles;
    int tr = blockIdx.x - e * maxTiles;
    int seg0 = offs[e];
    int nseg = offs[e + 1] - seg0;
    int rbase = tr * BM;
    if (rbase >= nseg) return;
    int nvalid = nseg - rbase; if (nvalid > BM) nvalid = BM;
    int row0 = seg0 + rbase;
    int f0 = blockIdx.y * BN;

    __shared__ bf16_t As[BM * PITCH];
    __shared__ bf16_t Bgs[BN * PITCH];
    __shared__ bf16_t Bus[BN * PITCH];

    int tid = threadIdx.x;
    int lane = tid & 63, wid = tid >> 6;
    int wm = wid >> 1, wn = wid & 1;
    int lr = lane & 15, lg = lane >> 4;

    int a_r = tid >> 1;
    int a_k = (tid & 1) * 16;
    int tkn = (a_r < nvalid) ? tok[row0 + a_r] : 0;
    const float* aptr = x + (size_t)tkn * HID + a_k;

    int b_n = tid & (BN - 1);
    int b_k = (tid >> 7) * 16;
    const float* gptr = wg + (size_t)e * HID * FINT + (size_t)b_k * FINT + f0 + b_n;
    const float* uptr = wu + (size_t)e * HID * FINT + (size_t)b_k * FINT + f0 + b_n;

    f32x4 zero = {0.f, 0.f, 0.f, 0.f};
    f32x4 accg[4][4], accu[4][4];
#pragma unroll
    for (int i = 0; i < 4; ++i)
#pragma unroll
        for (int j = 0; j < 4; ++j) { accg[i][j] = zero; accu[i][j] = zero; }

    float ar[16], bgr[16], bur[16];
    auto load_stage = [&](int kt) {
        const float4* a4 = (const float4*)(aptr + (size_t)kt * BK);
#pragma unroll
        for (int i = 0; i < 4; ++i) {
            float4 v = a4[i];
            ar[i * 4 + 0] = v.x; ar[i * 4 + 1] = v.y; ar[i * 4 + 2] = v.z; ar[i * 4 + 3] = v.w;
        }
        const float* gp = gptr + (size_t)kt * BK * FINT;
        const float* up = uptr + (size_t)kt * BK * FINT;
#pragma unroll
        for (int i = 0; i < 16; ++i) { bgr[i] = gp[(size_t)i * FINT]; bur[i] = up[(size_t)i * FINT]; }
    };
    auto write_stage = [&]() {
        bf16x8 w0, w1;
#pragma unroll
        for (int j = 0; j < 8; ++j) { w0[j] = (bf16_t)ar[j]; w1[j] = (bf16_t)ar[8 + j]; }
        *(bf16x8*)&As[a_r * PITCH + a_k] = w0;
        *(bf16x8*)&As[a_r * PITCH + a_k + 8] = w1;
#pragma unroll
        for (int j = 0; j < 8; ++j) { w0[j] = (bf16_t)bgr[j]; w1[j] = (bf16_t)bgr[8 + j]; }
        *(bf16x8*)&Bgs[b_n * PITCH + b_k] = w0;
        *(bf16x8*)&Bgs[b_n * PITCH + b_k + 8] = w1;
#pragma unroll
        for (int j = 0; j < 8; ++j) { w0[j] = (bf16_t)bur[j]; w1[j] = (bf16_t)bur[8 + j]; }
        *(bf16x8*)&Bus[b_n * PITCH + b_k] = w0;
        *(bf16x8*)&Bus[b_n * PITCH + b_k + 8] = w1;
    };
    auto compute = [&]() {
        bf16x8 a[4];
#pragma unroll
        for (int mi = 0; mi < 4; ++mi)
            a[mi] = *(const bf16x8*)&As[(wm * 64 + mi * 16 + lr) * PITCH + lg * 8];
#pragma unroll
        for (int ni = 0; ni < 4; ++ni) {
            bf16x8 bg = *(const bf16x8*)&Bgs[(wn * 64 + ni * 16 + lr) * PITCH + lg * 8];
            bf16x8 bu = *(const bf16x8*)&Bus[(wn * 64 + ni * 16 + lr) * PITCH + lg * 8];
#pragma unroll
            for (int mi = 0; mi < 4; ++mi) {
                accg[mi][ni] = __builtin_amdgcn_mfma_f32_16x16x32_bf16(a[mi], bg, accg[mi][ni], 0, 0, 0);
                accu[mi][ni] = __builtin_amdgcn_mfma_f32_16x16x32_bf16(a[mi], bu, accu[mi][ni], 0, 0, 0);
            }
        }
    };

    const int NK = HID / BK;
    load_stage(0);
    for (int kt = 0; kt < NK; ++kt) {
        __syncthreads();
        write_stage();
        __syncthreads();
        if (kt + 1 < NK) load_stage(kt + 1);
        compute();
    }

#pragma unroll
    for (int mi = 0; mi < 4; ++mi) {
        int rb = wm * 64 + mi * 16 + lg * 4;
#pragma unroll
        for (int ni = 0; ni < 4; ++ni) {
            int col = f0 + wn * 64 + ni * 16 + lr;
#pragma unroll
            for (int r = 0; r < 4; ++r) {
                int row = rb + r;
                if (row < nvalid) {
                    float g = accg[mi][ni][r], u = accu[mi][ni][r];
                    float h = (g / (1.f + __expf(-g))) * u;
                    h_buf[(size_t)(row0 + row) * FINT + col] = (bf16_t)h;
                }
            }
        }
    }
}

__global__ __launch_bounds__(256) void down_fb_kernel(
    const bf16_t* __restrict__ h_buf, const float* __restrict__ wd,
    const int* __restrict__ offs, const int* __restrict__ tok, const float* __restrict__ wslot,
    float* __restrict__ out, bf16_t* __restrict__ y_buf, int useY, int maxTiles)
{
    int e = blockIdx.x / maxTiles;
    int tr = blockIdx.x - e * maxTiles;
    int seg0 = offs[e];
    int nseg = offs[e + 1] - seg0;
    int rbase = tr * BM;
    if (rbase >= nseg) return;
    int nvalid = nseg - rbase; if (nvalid > BM) nvalid = BM;
    int row0 = seg0 + rbase;
    int h0 = blockIdx.y * BN;

    __shared__ bf16_t As[BM * PITCH];
    __shared__ bf16_t Bs[BN * PITCH];
    __shared__ float wsh[BM];
    __shared__ int   tsh[BM];

    int tid = threadIdx.x;
    if (tid < BM) {
        int v = tid < nvalid;
        wsh[tid] = v ? wslot[row0 + tid] : 0.f;
        tsh[tid] = v ? tok[row0 + tid] : 0;
    }

    int lane = tid & 63, wid = tid >> 6;
    int wm = wid >> 1, wn = wid & 1;
    int lr = lane & 15, lg = lane >> 4;

    int a_r = tid >> 1;
    int a_k = (tid & 1) * 16;
    const bf16_t* aptr = h_buf + (size_t)(row0 + a_r) * FINT + a_k;

    int b_n = tid & (BN - 1);
    int b_k = (tid >> 7) * 16;
    const float* dptr = wd + (size_t)e * FINT * HID + (size_t)b_k * HID + h0 + b_n;

    f32x4 zero = {0.f, 0.f, 0.f, 0.f};
    f32x4 acc[4][4];
#pragma unroll
    for (int i = 0; i < 4; ++i)
#pragma unroll
        for (int j = 0; j < 4; ++j) acc[i][j] = zero;

    bf16x8 ar0, ar1; float br[16];
    auto load_stage = [&](int kt) {
        const bf16x8* a8 = (const bf16x8*)(aptr + (size_t)kt * BK);
        ar0 = a8[0]; ar1 = a8[1];
        const float* dp = dptr + (size_t)kt * BK * HID;
#pragma unroll
        for (int i = 0; i < 16; ++i) br[i] = dp[(size_t)i * HID];
    };
    auto write_stage = [&]() {
        *(bf16x8*)&As[a_r * PITCH + a_k] = ar0;
        *(bf16x8*)&As[a_r * PITCH + a_k + 8] = ar1;
        bf16x8 w0, w1;
#pragma unroll
        for (int j = 0; j < 8; ++j) { w0[j] = (bf16_t)br[j]; w1[j] = (bf16_t)br[8 + j]; }
        *(bf16x8*)&Bs[b_n * PITCH + b_k] = w0;
        *(bf16x8*)&Bs[b_n * PITCH + b_k + 8] = w1;
    };
    auto compute = [&]() {
        bf16x8 a[4];
#pragma unroll
        for (int mi = 0; mi < 4; ++mi)
            a[mi] = *(const bf16x8*)&As[(wm * 64 + mi * 16 + lr) * PITCH + lg * 8];
#pragma unroll
        for (int ni = 0; ni < 4; ++ni) {
            bf16x8 b = *(const bf16x8*)&Bs[(wn * 64 + ni * 16 + lr) * PITCH + lg * 8];
#pragma unroll
            for (int mi = 0; mi < 4; ++mi)
                acc[mi][ni] = __builtin_amdgcn_mfma_f32_16x16x32_bf16(a[mi], b, acc[mi][ni], 0, 0, 0);
        }
    };

    const int NK = FINT / BK;
    load_stage(0);
    for (int kt = 0; kt < NK; ++kt) {
        __syncthreads();
        write_stage();
        __syncthreads();
        if (kt + 1 < NK) load_stage(kt + 1);
        compute();
    }

    if (useY) {
#pragma unroll
        for (int mi = 0; mi < 4; ++mi) {
            int rb = wm * 64 + mi * 16 + lg * 4;
#pragma unroll
            for (int ni = 0; ni < 4; ++ni) {
                int col = h0 + wn * 64 + ni * 16 + lr;
#pragma unroll
                for (int r = 0; r < 4; ++r) {
                    int row = rb + r;
                    if (row < nvalid)
                        y_buf[(size_t)(row0 + row) * HID + col] = (bf16_t)acc[mi][ni][r];
                }
            }
        }
    } else {
#pragma unroll
        for (int mi = 0; mi < 4; ++mi) {
            int rb = wm * 64 + mi * 16 + lg * 4;
#pragma unroll
            for (int ni = 0; ni < 4; ++ni) {
                int col = h0 + wn * 64 + ni * 16 + lr;
#pragma unroll
                for (int r = 0; r < 4; ++r) {
                    int row = rb + r;
                    if (row < nvalid)
                        atomicAdd(&out[(size_t)tsh[row] * HID + col], acc[mi][ni][r] * wsh[row]);
                }
            }
        }
    }
}

extern "C" void kernel_launch(void* const* d_in, const int* in_sizes, int n_in,
                              void* d_out, int out_size, void* d_ws, size_t ws_size,
                              hipStream_t stream)
{
    const float* x  = (const float*)d_in[0];
    const float* gw = (const float*)d_in[1];
    const float* wg = (const float*)d_in[2];
    const float* wu = (const float*)d_in[3];
    const float* wd = (const float*)d_in[4];
    float* out = (float*)d_out;
    int T = in_sizes[0] / HID;     // 4096
    int S2 = 2 * T;
    int maxTiles = (T + BM - 1) / BM;   // 32

    char* base = (char*)d_ws;
    int* cnt     = (int*)base;
    int* fill    = cnt + 8;
    int* offs    = cnt + 16;
    int* topk_id = cnt + 32;
    float* topk_w = (float*)(topk_id + S2);
    int* tok     = (int*)(topk_w + S2);
    float* wslot = (float*)(tok + S2 + 256);
    int* slot_of = (int*)(wslot + S2 + 256);
    size_t small_end = (size_t)((char*)(slot_of + S2) - base);
    size_t cur = (small_end + 255) & ~(size_t)255;
    auto take = [&](size_t bytes) -> size_t {
        size_t o = cur; cur += bytes; cur = (cur + 255) & ~(size_t)255; return o;
    };
    size_t wbytes = (size_t)NEXP * HID * FINT * 2;
    size_t o_xb  = take((size_t)T * HID * 2);
    size_t o_wgb = take(wbytes);
    size_t o_wub = take(wbytes);
    size_t o_wdb = take(wbytes);
    size_t o_h   = take((size_t)(S2 + 256) * FINT * 2);
    size_t needA = cur;
    size_t o_y   = take((size_t)(S2 + 256) * HID * 2);
    size_t needY = cur;

    int useNew = (ws_size >= needA);
    int useY   = (ws_size >= needY);

    bf16_t* xb = useNew ? (bf16_t*)(base + o_xb) : nullptr;

    hipMemsetAsync(base, 0, 64, stream);   // cnt + fill
    router_kernel<<<T, 64, 0, stream>>>(x, gw, cnt, topk_id, topk_w, xb, T);
    offsets_kernel<<<1, 64, 0, stream>>>(cnt, offs);
    scatter_kernel<<<(T + 255) / 256, 256, 0, stream>>>(topk_id, topk_w, offs, fill, tok, wslot, slot_of, T);

    if (useNew) {
        bf16_t* wgb = (bf16_t*)(base + o_wgb);
        bf16_t* wub = (bf16_t*)(base + o_wub);
        bf16_t* wdb = (bf16_t*)(base + o_wdb);
        bf16_t* h_buf = (bf16_t*)(base + o_h);
        bf16_t* y_buf = (bf16_t*)(base + o_y);

        // wg, wu: [E][H][F] -> [E][F][H]
        int gridW = NEXP * (HID / 64) * (FINT / 64);   // 5632
        cvt_t_kernel<<<gridW, 256, 0, stream>>>(wg, wgb, HID, FINT);
        cvt_t_kernel<<<gridW, 256, 0, stream>>>(wu, wub, HID, FINT);
        // wd: [E][F][H] -> [E][H][F]
        cvt_t_kernel<<<gridW, 256, 0, stream>>>(wd, wdb, FINT, HID);

        int ggrid = NEXP * (FINT / BN) * maxTiles;     // 2816
        gateup2_kernel<<<ggrid, 256, 0, stream>>>(xb, wgb, wub, offs, tok, h_buf, maxTiles);

        int dgrid = NEXP * (HID / BN) * maxTiles;      // 4096
        if (!useY) hipMemsetAsync(out, 0, (size_t)out_size * sizeof(float), stream);
        down2_kernel<<<dgrid, 256, 0, stream>>>(h_buf, wdb, offs, tok, wslot, out, y_buf, useY, maxTiles);
        if (useY) combine_kernel<<<T, 256, 0, stream>>>(y_buf, slot_of, topk_w, out, T);
    } else {
        // fallback: round-1 layout (h, y right after small block)
        size_t fcur = (small_end + 255) & ~(size_t)255;
        bf16_t* h_buf = (bf16_t*)(base + fcur);
        size_t hbytes = (size_t)(S2 + 256) * FINT * 2;
        size_t yoff = (fcur + hbytes + 255) & ~(size_t)255;
        bf16_t* y_buf = (bf16_t*)(base + yoff);
        size_t ybytes = (size_t)(S2 + 256) * HID * 2;
        int useYf = (yoff + ybytes <= ws_size) ? 1 : 0;

        dim3 ggrid(NEXP * maxTiles, FINT / BN);
        gateup_fb_kernel<<<ggrid, 256, 0, stream>>>(x, wg, wu, offs, tok, h_buf, maxTiles);
        dim3 dgrid(NEXP * maxTiles, HID / BN);
        if (!useYf) hipMemsetAsync(out, 0, (size_t)out_size * sizeof(float), stream);
        down_fb_kernel<<<dgrid, 256, 0, stream>>>(h_buf, wd, offs, tok, wslot, out, y_buf, useYf, maxTiles);
        if (useYf) combine_kernel<<<T, 256, 0, stream>>>(y_buf, slot_of, topk_w, out, T);
    }
}

// Round 4
// 504.529 us; speedup vs baseline: 2.9810x; 1.0337x over previous
//
#include <hip/hip_runtime.h>
#include <hip/hip_bf16.h>

#define HID  2048
#define NEXP 8
#define FINT 1408
#define TM   128        // slot-tile (M)
#define BK   32
#define GU_NP 11        // gateup f-panels of 128
#define DN_NP 8         // down col-panels of 256
#define MAXT 96

typedef __bf16 bf16_t;
typedef __bf16 bf16x8 __attribute__((ext_vector_type(8)));
typedef float  f32x4  __attribute__((ext_vector_type(4)));

#define AS1 __attribute__((address_space(1)))
#define AS3 __attribute__((address_space(3)))

__device__ __forceinline__ void gll16(const void* g, void* l) {
    __builtin_amdgcn_global_load_lds((const AS1 void*)g, (AS3 void*)l, 16, 0, 0);
}

#define VMCNT6() asm volatile("s_waitcnt vmcnt(6)" ::: "memory")
#define VMCNT0() asm volatile("s_waitcnt vmcnt(0)" ::: "memory")
#define SB0() __builtin_amdgcn_sched_barrier(0)

// ---------------- router: logits -> softmax -> top2 + counts (+ x->bf16) ----------------
__global__ __launch_bounds__(64) void router_kernel(
    const float* __restrict__ x, const float* __restrict__ gw,
    int* __restrict__ cnt, int* __restrict__ topk_id, float* __restrict__ topk_w,
    bf16_t* __restrict__ xb, int T)
{
    int t = blockIdx.x;
    if (t >= T) return;
    int lane = threadIdx.x;
    float acc[NEXP];
#pragma unroll
    for (int e = 0; e < NEXP; ++e) acc[e] = 0.f;
    const float* xr = x + (size_t)t * HID;
    bf16_t* xo = xb + (size_t)t * HID;
    for (int i = lane; i < HID; i += 64) {
        float xv = xr[i];
        xo[i] = (bf16_t)xv;
        const float4* g4 = (const float4*)(gw + (size_t)i * NEXP);
        float4 a = g4[0], b = g4[1];
        acc[0] += xv * a.x; acc[1] += xv * a.y; acc[2] += xv * a.z; acc[3] += xv * a.w;
        acc[4] += xv * b.x; acc[5] += xv * b.y; acc[6] += xv * b.z; acc[7] += xv * b.w;
    }
#pragma unroll
    for (int d = 1; d < 64; d <<= 1) {
#pragma unroll
        for (int e = 0; e < NEXP; ++e) acc[e] += __shfl_xor(acc[e], d, 64);
    }
    float mx = acc[0];
#pragma unroll
    for (int e = 1; e < NEXP; ++e) mx = fmaxf(mx, acc[e]);
    float p[NEXP]; float s = 0.f;
#pragma unroll
    for (int e = 0; e < NEXP; ++e) { p[e] = expf(acc[e] - mx); s += p[e]; }
    float inv = 1.f / s;
    int i1 = 0;
#pragma unroll
    for (int e = 1; e < NEXP; ++e) if (acc[e] > acc[i1]) i1 = e;
    int i2 = (i1 == 0) ? 1 : 0;
#pragma unroll
    for (int e = 0; e < NEXP; ++e) if (e != i1 && acc[e] > acc[i2]) i2 = e;
    if (lane == 0) {
        topk_id[t * 2 + 0] = i1; topk_id[t * 2 + 1] = i2;
        topk_w[t * 2 + 0] = p[i1] * inv; topk_w[t * 2 + 1] = p[i2] * inv;
        atomicAdd(&cnt[i1], 1); atomicAdd(&cnt[i2], 1);
    }
}

// ---------------- offsets + tile list ----------------
__global__ void offsets_kernel(const int* __restrict__ cnt, int* __restrict__ offs,
                               int* __restrict__ tile_e, int* __restrict__ tile_r,
                               int* __restrict__ ntl)
{
    if (threadIdx.x == 0) {
        int s = 0;
        for (int e = 0; e < NEXP; ++e) { offs[e] = s; s += cnt[e]; }
        offs[NEXP] = s;
        int k = 0;
        for (int e = 0; e < NEXP; ++e)
            for (int rb = 0; rb < cnt[e] && k < MAXT; rb += TM) { tile_e[k] = e; tile_r[k] = rb; ++k; }
        ntl[0] = k;
    }
}

__global__ void scatter_kernel(
    const int* __restrict__ topk_id, const int* __restrict__ offs, int* __restrict__ fill,
    int* __restrict__ tok, int* __restrict__ slot_of, int T)
{
    int t = blockIdx.x * blockDim.x + threadIdx.x;
    if (t >= T) return;
#pragma unroll
    for (int k = 0; k < 2; ++k) {
        int e = topk_id[t * 2 + k];
        int pos = atomicAdd(&fill[e], 1);
        int slot = offs[e] + pos;
        tok[slot] = t;
        slot_of[t * 2 + k] = slot;
    }
}

// ------- transpose-convert: in fp32 [E][R][C] -> out bf16 [E][C][R] -------
__global__ __launch_bounds__(256) void cvt_t_kernel(
    const float* __restrict__ in, bf16_t* __restrict__ outb, int R, int C)
{
    int tilesR = R >> 6, tilesC = C >> 6;
    int per = tilesR * tilesC;
    int e = blockIdx.x / per;
    int rem = blockIdx.x - e * per;
    int tr = rem / tilesC, tc = rem - tr * tilesC;
    const float* src = in + (size_t)e * R * C + (size_t)(tr * 64) * C + tc * 64;
    bf16_t* dst = outb + (size_t)e * R * C + (size_t)(tc * 64) * R + tr * 64;

    __shared__ float tile[64][65];
    int tid = threadIdx.x;
    int rr = tid >> 4;
    int cc = (tid & 15) * 4;
#pragma unroll
    for (int i = 0; i < 4; ++i) {
        float4 v = *(const float4*)(src + (size_t)(rr + i * 16) * C + cc);
        tile[rr + i * 16][cc + 0] = v.x; tile[rr + i * 16][cc + 1] = v.y;
        tile[rr + i * 16][cc + 2] = v.z; tile[rr + i * 16][cc + 3] = v.w;
    }
    __syncthreads();
    int oc = tid >> 2;
    int og = (tid & 3) * 16;
    bf16_t* dp = dst + (size_t)oc * R + og;
    bf16x8 o0, o1;
#pragma unroll
    for (int j = 0; j < 8; ++j) { o0[j] = (bf16_t)tile[og + j][oc]; o1[j] = (bf16_t)tile[og + 8 + j][oc]; }
    *(bf16x8*)dp = o0;
    *(bf16x8*)(dp + 8) = o1;
}

// ======== gate+up GEMM: 128 slots x (128f x {gate,up}) tile, dist-2 counted vmcnt ========
__global__ __launch_bounds__(256, 2) void gateup3_kernel(
    const bf16_t* __restrict__ xb, const bf16_t* __restrict__ wgb, const bf16_t* __restrict__ wub,
    const int* __restrict__ offs, const int* __restrict__ tok,
    const int* __restrict__ tile_e, const int* __restrict__ tile_r, const int* __restrict__ ntl,
    bf16_t* __restrict__ h_buf)
{
    __shared__ bf16_t smem[36864];   // A: 3*4096, B: 3*8192 (72 KB) ; epilogue reuses [0,16384)
    const int ntiles = ntl[0];
    const int nitems = ntiles * GU_NP;
    const int tid = threadIdx.x;
    const int lane = tid & 63, w = tid >> 6;
    const int lr = lane & 15, lg = lane >> 4;
    const int rl = lane >> 2;
    const int sw8 = ((lane & 3) ^ ((lane >> 3) & 3)) * 8;   // source k pre-swizzle
    const int ksw = (lg ^ ((lr >> 1) & 3)) * 8;             // read-side swizzle

    for (int item = blockIdx.x; item < nitems; item += (int)gridDim.x) {
        const int ti = item / GU_NP;
        const int fp = item - ti * GU_NP;
        const int e = tile_e[ti], rbase = tile_r[ti];
        const int seg0 = offs[e];
        const int nvalid = min(offs[e + 1] - seg0 - rbase, TM);
        const int row0 = seg0 + rbase;
        const int f0 = fp * 128;

        const bf16_t* aP[2];
#pragma unroll
        for (int i = 0; i < 2; ++i) {
            int r = w * 32 + i * 16 + rl;
            int tk = tok[row0 + min(r, nvalid - 1)];
            aP[i] = xb + (size_t)tk * HID + sw8;
        }
        const bf16_t* bP[4];
#pragma unroll
        for (int j = 0; j < 4; ++j) {
            int br = w * 64 + j * 16 + rl;                  // 0..255: <128 gate, >=128 up
            const bf16_t* W = (br < 128) ? wgb : wub;
            bP[j] = W + ((size_t)e * FINT + f0 + (br & 127)) * HID + sw8;
        }

        f32x4 acc[8][4];
#pragma unroll
        for (int mi = 0; mi < 8; ++mi)
#pragma unroll
            for (int ni = 0; ni < 4; ++ni) acc[mi][ni] = (f32x4){0.f, 0.f, 0.f, 0.f};

        auto STAGE = [&](int b, int kt) {
            int k0 = kt * BK;
            bf16_t* A = smem + b * 4096;
            bf16_t* B = smem + 12288 + b * 8192;
            gll16(aP[0] + k0, A + (w * 2 + 0) * 512);
            gll16(aP[1] + k0, A + (w * 2 + 1) * 512);
            gll16(bP[0] + k0, B + (w * 4 + 0) * 512);
            gll16(bP[1] + k0, B + (w * 4 + 1) * 512);
            gll16(bP[2] + k0, B + (w * 4 + 2) * 512);
            gll16(bP[3] + k0, B + (w * 4 + 3) * 512);
        };
        auto COMPUTE = [&](int b) {
            const bf16_t* A = smem + b * 4096;
            const bf16_t* B = smem + 12288 + b * 8192;
            bf16x8 bfr[4];
#pragma unroll
            for (int ni = 0; ni < 4; ++ni)
                bfr[ni] = *(const bf16x8*)&B[(w * 64 + ni * 16 + lr) * BK + ksw];
#pragma unroll
            for (int mi = 0; mi < 8; ++mi) {
                bf16x8 a = *(const bf16x8*)&A[(mi * 16 + lr) * BK + ksw];
#pragma unroll
                for (int ni = 0; ni < 4; ++ni)
                    acc[mi][ni] = __builtin_amdgcn_mfma_f32_16x16x32_bf16(a, bfr[ni], acc[mi][ni], 0, 0, 0);
            }
        };

        const int NK = HID / BK;   // 64
        STAGE(0, 0); STAGE(1, 1);
        int c0 = 0, c1 = 1, c2 = 2;
        for (int kt = 0; kt < NK - 1; ++kt) {
            SB0(); VMCNT6(); __builtin_amdgcn_s_barrier(); SB0();
            if (kt + 2 < NK) STAGE(c2, kt + 2);
            SB0();
            COMPUTE(c0);
            int t = c0; c0 = c1; c1 = c2; c2 = t;
        }
        SB0(); VMCNT0(); __builtin_amdgcn_s_barrier(); SB0();
        COMPUTE(c0);
        __syncthreads();

        // epilogue: up waves park u in LDS (bf16 [128][128]), gate waves combine
        if (w >= 2) {
#pragma unroll
            for (int mi = 0; mi < 8; ++mi)
#pragma unroll
                for (int ni = 0; ni < 4; ++ni)
#pragma unroll
                    for (int rr = 0; rr < 4; ++rr) {
                        int row = mi * 16 + lg * 4 + rr;
                        int col = (w - 2) * 64 + ni * 16 + lr;
                        smem[row * 128 + col] = (bf16_t)acc[mi][ni][rr];
                    }
        }
        __syncthreads();
        if (w < 2) {
#pragma unroll
            for (int mi = 0; mi < 8; ++mi)
#pragma unroll
                for (int ni = 0; ni < 4; ++ni)
#pragma unroll
                    for (int rr = 0; rr < 4; ++rr) {
                        int row = mi * 16 + lg * 4 + rr;
                        int col = w * 64 + ni * 16 + lr;
                        float g = acc[mi][ni][rr];
                        float u = (float)smem[row * 128 + col];
                        float h = (g / (1.f + __expf(-g))) * u;
                        if (row < nvalid)
                            h_buf[(size_t)(row0 + row) * FINT + f0 + col] = (bf16_t)h;
                    }
        }
        __syncthreads();
    }
}

// ======== down GEMM: 128 slots x 256 h-cols tile, dist-2 counted vmcnt ========
__global__ __launch_bounds__(256, 2) void down3_kernel(
    const bf16_t* __restrict__ h_buf, const bf16_t* __restrict__ wdb,
    const int* __restrict__ offs, const int* __restrict__ tile_e, const int* __restrict__ tile_r,
    const int* __restrict__ ntl, bf16_t* __restrict__ y_buf)
{
    __shared__ bf16_t smem[36864];
    const int ntiles = ntl[0];
    const int nitems = ntiles * DN_NP;
    const int tid = threadIdx.x;
    const int lane = tid & 63, w = tid >> 6;
    const int lr = lane & 15, lg = lane >> 4;
    const int rl = lane >> 2;
    const int sw8 = ((lane & 3) ^ ((lane >> 3) & 3)) * 8;
    const int ksw = (lg ^ ((lr >> 1) & 3)) * 8;

    for (int item = blockIdx.x; item < nitems; item += (int)gridDim.x) {
        const int ti = item / DN_NP;
        const int hp = item - ti * DN_NP;
        const int e = tile_e[ti], rbase = tile_r[ti];
        const int seg0 = offs[e];
        const int nvalid = min(offs[e + 1] - seg0 - rbase, TM);
        const int row0 = seg0 + rbase;
        const int h0 = hp * 256;

        const bf16_t* aP[2];
#pragma unroll
        for (int i = 0; i < 2; ++i) {
            int r = w * 32 + i * 16 + rl;
            aP[i] = h_buf + (size_t)(row0 + r) * FINT + sw8;
        }
        const bf16_t* bP[4];
#pragma unroll
        for (int j = 0; j < 4; ++j) {
            int br = w * 64 + j * 16 + rl;
            bP[j] = wdb + ((size_t)e * HID + h0 + br) * FINT + sw8;
        }

        f32x4 acc[8][4];
#pragma unroll
        for (int mi = 0; mi < 8; ++mi)
#pragma unroll
            for (int ni = 0; ni < 4; ++ni) acc[mi][ni] = (f32x4){0.f, 0.f, 0.f, 0.f};

        auto STAGE = [&](int b, int kt) {
            int k0 = kt * BK;
            bf16_t* A = smem + b * 4096;
            bf16_t* B = smem + 12288 + b * 8192;
            gll16(aP[0] + k0, A + (w * 2 + 0) * 512);
            gll16(aP[1] + k0, A + (w * 2 + 1) * 512);
            gll16(bP[0] + k0, B + (w * 4 + 0) * 512);
            gll16(bP[1] + k0, B + (w * 4 + 1) * 512);
            gll16(bP[2] + k0, B + (w * 4 + 2) * 512);
            gll16(bP[3] + k0, B + (w * 4 + 3) * 512);
        };
        auto COMPUTE = [&](int b) {
            const bf16_t* A = smem + b * 4096;
            const bf16_t* B = smem + 12288 + b * 8192;
            bf16x8 bfr[4];
#pragma unroll
            for (int ni = 0; ni < 4; ++ni)
                bfr[ni] = *(const bf16x8*)&B[(w * 64 + ni * 16 + lr) * BK + ksw];
#pragma unroll
            for (int mi = 0; mi < 8; ++mi) {
                bf16x8 a = *(const bf16x8*)&A[(mi * 16 + lr) * BK + ksw];
#pragma unroll
                for (int ni = 0; ni < 4; ++ni)
                    acc[mi][ni] = __builtin_amdgcn_mfma_f32_16x16x32_bf16(a, bfr[ni], acc[mi][ni], 0, 0, 0);
            }
        };

        const int NK = FINT / BK;  // 44
        STAGE(0, 0); STAGE(1, 1);
        int c0 = 0, c1 = 1, c2 = 2;
        for (int kt = 0; kt < NK - 1; ++kt) {
            SB0(); VMCNT6(); __builtin_amdgcn_s_barrier(); SB0();
            if (kt + 2 < NK) STAGE(c2, kt + 2);
            SB0();
            COMPUTE(c0);
            int t = c0; c0 = c1; c1 = c2; c2 = t;
        }
        SB0(); VMCNT0(); __builtin_amdgcn_s_barrier(); SB0();
        COMPUTE(c0);

#pragma unroll
        for (int mi = 0; mi < 8; ++mi)
#pragma unroll
            for (int ni = 0; ni < 4; ++ni)
#pragma unroll
                for (int rr = 0; rr < 4; ++rr) {
                    int row = mi * 16 + lg * 4 + rr;
                    int col = w * 64 + ni * 16 + lr;
                    if (row < nvalid)
                        y_buf[(size_t)(row0 + row) * HID + h0 + col] = (bf16_t)acc[mi][ni][rr];
                }
        __syncthreads();
    }
}

// ---------------- combine: out[t] = w0*y[s0] + w1*y[s1] ----------------
__global__ __launch_bounds__(256) void combine_kernel(
    const bf16_t* __restrict__ y, const int* __restrict__ slot_of,
    const float* __restrict__ topk_w, float* __restrict__ out, int T)
{
    int t = blockIdx.x;
    int tid = threadIdx.x;
    int s0 = slot_of[t * 2], s1 = slot_of[t * 2 + 1];
    float w0 = topk_w[t * 2], w1 = topk_w[t * 2 + 1];
    const bf16x8* y0 = (const bf16x8*)(y + (size_t)s0 * HID);
    const bf16x8* y1 = (const bf16x8*)(y + (size_t)s1 * HID);
    bf16x8 v0 = y0[tid], v1 = y1[tid];
    float* op = out + (size_t)t * HID + tid * 8;
#pragma unroll
    for (int j = 0; j < 8; ++j)
        op[j] = w0 * (float)v0[j] + w1 * (float)v1[j];
}

extern "C" void kernel_launch(void* const* d_in, const int* in_sizes, int n_in,
                              void* d_out, int out_size, void* d_ws, size_t ws_size,
                              hipStream_t stream)
{
    const float* x  = (const float*)d_in[0];
    const float* gw = (const float*)d_in[1];
    const float* wg = (const float*)d_in[2];
    const float* wu = (const float*)d_in[3];
    const float* wd = (const float*)d_in[4];
    float* out = (float*)d_out;
    int T = in_sizes[0] / HID;     // 4096
    int S2 = 2 * T;

    char* base = (char*)d_ws;
    int* cnt     = (int*)base;                 // 8
    int* fill    = cnt + 8;                    // 8
    int* offs    = cnt + 16;                   // 9 (pad to 12)
    int* ntl     = cnt + 28;                   // 1 (pad to 4)
    int* tile_e  = cnt + 32;                   // 96
    int* tile_r  = cnt + 128;                  // 96
    int* topk_id = cnt + 224;                  // 2T
    float* topk_w = (float*)(topk_id + S2);    // 2T
    int* tok     = (int*)(topk_w + S2);        // 2T + 256 pad
    int* slot_of = tok + S2 + 256;             // 2T
    size_t small_end = (size_t)((char*)(slot_of + S2) - base);
    size_t cur = (small_end + 255) & ~(size_t)255;
    auto take = [&](size_t bytes) -> size_t {
        size_t o = cur; cur += bytes; cur = (cur + 255) & ~(size_t)255; return o;
    };
    size_t wbytes = (size_t)NEXP * HID * FINT * 2;
    size_t o_xb  = take((size_t)T * HID * 2);
    size_t o_wgb = take(wbytes);
    size_t o_wub = take(wbytes);
    size_t o_wdb = take(wbytes);
    size_t o_h   = take((size_t)(S2 + 256) * FINT * 2);
    size_t o_y   = take((size_t)(S2 + 256) * HID * 2);
    (void)ws_size;

    bf16_t* xb   = (bf16_t*)(base + o_xb);
    bf16_t* wgb  = (bf16_t*)(base + o_wgb);
    bf16_t* wub  = (bf16_t*)(base + o_wub);
    bf16_t* wdb  = (bf16_t*)(base + o_wdb);
    bf16_t* h_buf = (bf16_t*)(base + o_h);
    bf16_t* y_buf = (bf16_t*)(base + o_y);

    hipMemsetAsync(base, 0, 64, stream);   // cnt + fill

    router_kernel<<<T, 64, 0, stream>>>(x, gw, cnt, topk_id, topk_w, xb, T);
    offsets_kernel<<<1, 64, 0, stream>>>(cnt, offs, tile_e, tile_r, ntl);
    scatter_kernel<<<(T + 255) / 256, 256, 0, stream>>>(topk_id, offs, fill, tok, slot_of, T);

    int gridW = NEXP * (HID / 64) * (FINT / 64);   // 5632
    cvt_t_kernel<<<gridW, 256, 0, stream>>>(wg, wgb, HID, FINT);   // [E][F][H]
    cvt_t_kernel<<<gridW, 256, 0, stream>>>(wu, wub, HID, FINT);   // [E][F][H]
    cvt_t_kernel<<<gridW, 256, 0, stream>>>(wd, wdb, FINT, HID);   // [E][H][F]

    gateup3_kernel<<<512, 256, 0, stream>>>(xb, wgb, wub, offs, tok, tile_e, tile_r, ntl, h_buf);
    down3_kernel<<<512, 256, 0, stream>>>(h_buf, wdb, offs, tile_e, tile_r, ntl, y_buf);
    combine_kernel<<<T, 256, 0, stream>>>(y_buf, slot_of, topk_w, out, T);
}

// Round 5
// 493.432 us; speedup vs baseline: 3.0480x; 1.0225x over previous
//
#include <hip/hip_runtime.h>
#include <hip/hip_bf16.h>

#define HID  2048
#define NEXP 8
#define FINT 1408
#define TM   256        // slot-tile (M)
#define BK   32
#define GU_NPAN 88      // 8 experts x 11 f-panels (128 f each -> gate+up = 256 cols)
#define DN_NPAN 64      // 8 experts x 8 h-panels (256 h each)

typedef __bf16 bf16_t;
typedef __bf16 bf16x8 __attribute__((ext_vector_type(8)));
typedef float  f32x4  __attribute__((ext_vector_type(4)));

#define AS1 __attribute__((address_space(1)))
#define AS3 __attribute__((address_space(3)))

__device__ __forceinline__ void gll16(const void* g, void* l) {
    __builtin_amdgcn_global_load_lds((const AS1 void*)g, (AS3 void*)l, 16, 0, 0);
}

#define VMCNT4() asm volatile("s_waitcnt vmcnt(4)" ::: "memory")
#define VMCNT0() asm volatile("s_waitcnt vmcnt(0)" ::: "memory")
#define SB0() __builtin_amdgcn_sched_barrier(0)

// ---------------- router: logits -> softmax -> top2 + counts (+ x->bf16) ----------------
__global__ __launch_bounds__(64) void router_kernel(
    const float* __restrict__ x, const float* __restrict__ gw,
    int* __restrict__ cnt, int* __restrict__ topk_id, float* __restrict__ topk_w,
    bf16_t* __restrict__ xb, int T)
{
    int t = blockIdx.x;
    if (t >= T) return;
    int lane = threadIdx.x;
    float acc[NEXP];
#pragma unroll
    for (int e = 0; e < NEXP; ++e) acc[e] = 0.f;
    const float* xr = x + (size_t)t * HID;
    bf16_t* xo = xb + (size_t)t * HID;
    for (int i = lane; i < HID; i += 64) {
        float xv = xr[i];
        xo[i] = (bf16_t)xv;
        const float4* g4 = (const float4*)(gw + (size_t)i * NEXP);
        float4 a = g4[0], b = g4[1];
        acc[0] += xv * a.x; acc[1] += xv * a.y; acc[2] += xv * a.z; acc[3] += xv * a.w;
        acc[4] += xv * b.x; acc[5] += xv * b.y; acc[6] += xv * b.z; acc[7] += xv * b.w;
    }
#pragma unroll
    for (int d = 1; d < 64; d <<= 1) {
#pragma unroll
        for (int e = 0; e < NEXP; ++e) acc[e] += __shfl_xor(acc[e], d, 64);
    }
    float mx = acc[0];
#pragma unroll
    for (int e = 1; e < NEXP; ++e) mx = fmaxf(mx, acc[e]);
    float p[NEXP]; float s = 0.f;
#pragma unroll
    for (int e = 0; e < NEXP; ++e) { p[e] = expf(acc[e] - mx); s += p[e]; }
    float inv = 1.f / s;
    int i1 = 0;
#pragma unroll
    for (int e = 1; e < NEXP; ++e) if (acc[e] > acc[i1]) i1 = e;
    int i2 = (i1 == 0) ? 1 : 0;
#pragma unroll
    for (int e = 0; e < NEXP; ++e) if (e != i1 && acc[e] > acc[i2]) i2 = e;
    if (lane == 0) {
        topk_id[t * 2 + 0] = i1; topk_id[t * 2 + 1] = i2;
        topk_w[t * 2 + 0] = p[i1] * inv; topk_w[t * 2 + 1] = p[i2] * inv;
        atomicAdd(&cnt[i1], 1); atomicAdd(&cnt[i2], 1);
    }
}

// ---------------- offsets + per-XCD panel-affine item lists ----------------
__global__ void offsets_kernel(const int* __restrict__ cnt, int* __restrict__ offs,
                               int* __restrict__ gbase, int* __restrict__ gcount,
                               int* __restrict__ dbase, int* __restrict__ dcount,
                               int* __restrict__ gu, int* __restrict__ dn)
{
    if (threadIdx.x == 0) {
        int s = 0;
        for (int e = 0; e < NEXP; ++e) { offs[e] = s; s += cnt[e]; }
        offs[NEXP] = s;
        int k = 0;
        for (int x = 0; x < 8; ++x) {
            gbase[x] = k;
            for (int p = x; p < GU_NPAN; p += 8) {
                int e = p / 11, fp = p - e * 11;
                int nt = (cnt[e] + TM - 1) / TM;
                for (int t = 0; t < nt; ++t) gu[k++] = (e << 10) | (fp << 6) | t;
            }
            gcount[x] = k - gbase[x];
        }
        k = 0;
        for (int x = 0; x < 8; ++x) {
            dbase[x] = k;
            for (int p = x; p < DN_NPAN; p += 8) {
                int e = p >> 3, hp = p & 7;
                int nt = (cnt[e] + TM - 1) / TM;
                for (int t = 0; t < nt; ++t) dn[k++] = (e << 10) | (hp << 6) | t;
            }
            dcount[x] = k - dbase[x];
        }
    }
}

__global__ void scatter_kernel(
    const int* __restrict__ topk_id, const int* __restrict__ offs, int* __restrict__ fill,
    int* __restrict__ tok, int* __restrict__ slot_of, int T)
{
    int t = blockIdx.x * blockDim.x + threadIdx.x;
    if (t >= T) return;
#pragma unroll
    for (int k = 0; k < 2; ++k) {
        int e = topk_id[t * 2 + k];
        int pos = atomicAdd(&fill[e], 1);
        int slot = offs[e] + pos;
        tok[slot] = t;
        slot_of[t * 2 + k] = slot;
    }
}

// ------- transpose-convert: in fp32 [E][R][C] -> out bf16 [E][C][R] -------
__global__ __launch_bounds__(256) void cvt_t_kernel(
    const float* __restrict__ in, bf16_t* __restrict__ outb, int R, int C)
{
    int tilesR = R >> 6, tilesC = C >> 6;
    int per = tilesR * tilesC;
    int e = blockIdx.x / per;
    int rem = blockIdx.x - e * per;
    int tr = rem / tilesC, tc = rem - tr * tilesC;
    const float* src = in + (size_t)e * R * C + (size_t)(tr * 64) * C + tc * 64;
    bf16_t* dst = outb + (size_t)e * R * C + (size_t)(tc * 64) * R + tr * 64;

    __shared__ float tile[64][65];
    int tid = threadIdx.x;
    int rr = tid >> 4;
    int cc = (tid & 15) * 4;
#pragma unroll
    for (int i = 0; i < 4; ++i) {
        float4 v = *(const float4*)(src + (size_t)(rr + i * 16) * C + cc);
        tile[rr + i * 16][cc + 0] = v.x; tile[rr + i * 16][cc + 1] = v.y;
        tile[rr + i * 16][cc + 2] = v.z; tile[rr + i * 16][cc + 3] = v.w;
    }
    __syncthreads();
    int oc = tid >> 2;
    int og = (tid & 3) * 16;
    bf16_t* dp = dst + (size_t)oc * R + og;
    bf16x8 o0, o1;
#pragma unroll
    for (int j = 0; j < 8; ++j) { o0[j] = (bf16_t)tile[og + j][oc]; o1[j] = (bf16_t)tile[og + 8 + j][oc]; }
    *(bf16x8*)dp = o0;
    *(bf16x8*)(dp + 8) = o1;
}

// ======== gate+up GEMM: 256 slots x (128f x {gate,up}), 8 waves, XCD-affine ========
__global__ __launch_bounds__(512, 2) void gateup3_kernel(
    const bf16_t* __restrict__ xb, const bf16_t* __restrict__ wgb, const bf16_t* __restrict__ wub,
    const int* __restrict__ offs, const int* __restrict__ tok,
    const int* __restrict__ gbase, const int* __restrict__ gcount, const int* __restrict__ gu,
    bf16_t* __restrict__ h_buf)
{
    __shared__ bf16_t smem[49152];   // A: 3 x 8192, B: 3 x 8192 (96 KB)
    const int tid = threadIdx.x;
    const int lane = tid & 63, w = tid >> 6;      // 8 waves
    const int wm = w >> 1, wn = w & 1;            // 4 x 2 wave grid (64r x 128c each)
    const int lr = lane & 15, lg = lane >> 4;
    const int rl = lane >> 2;
    const int sw8 = ((lane & 3) ^ ((lane >> 3) & 3)) * 8;   // source k pre-swizzle
    const int ksw = (lg ^ ((lr >> 1) & 3)) * 8;             // read-side swizzle

    const int xcd = blockIdx.x & 7, slot = blockIdx.x >> 3;  // 32 slots per xcd
    const int icnt = gcount[xcd], ib = gbase[xcd];

    for (int ii = slot; ii < icnt; ii += 32) {
        const int it = gu[ib + ii];
        const int e = it >> 10, fp = (it >> 6) & 15, tr = it & 63;
        const int seg0 = offs[e];
        const int rbase = tr * TM;
        const int nvalid = min(offs[e + 1] - seg0 - rbase, TM);
        const int row0 = seg0 + rbase;
        const int f0 = fp * 128;

        const bf16_t* aP[2];
#pragma unroll
        for (int i = 0; i < 2; ++i) {
            int r = (w * 2 + i) * 16 + rl;
            int tk = tok[row0 + min(r, nvalid - 1)];
            aP[i] = xb + (size_t)tk * HID + sw8;
        }
        const bf16_t* bP[2];
#pragma unroll
        for (int i = 0; i < 2; ++i) {
            int br = (w * 2 + i) * 16 + rl;                 // 0..255: <128 gate, >=128 up
            const bf16_t* W = (br < 128) ? wgb : wub;
            bP[i] = W + ((size_t)e * FINT + f0 + (br & 127)) * HID + sw8;
        }

        f32x4 acc[4][8];
#pragma unroll
        for (int mi = 0; mi < 4; ++mi)
#pragma unroll
            for (int ni = 0; ni < 8; ++ni) acc[mi][ni] = (f32x4){0.f, 0.f, 0.f, 0.f};

        auto STAGE = [&](int b, int kt) {
            int k0 = kt * BK;
            bf16_t* A = smem + b * 8192;
            bf16_t* B = smem + 24576 + b * 8192;
            gll16(aP[0] + k0, A + (w * 2 + 0) * 512);
            gll16(aP[1] + k0, A + (w * 2 + 1) * 512);
            gll16(bP[0] + k0, B + (w * 2 + 0) * 512);
            gll16(bP[1] + k0, B + (w * 2 + 1) * 512);
        };
        auto COMPUTE = [&](int b) {
            const bf16_t* A = smem + b * 8192;
            const bf16_t* B = smem + 24576 + b * 8192;
            bf16x8 bfr[8];
#pragma unroll
            for (int ni = 0; ni < 8; ++ni)
                bfr[ni] = *(const bf16x8*)&B[(wn * 128 + ni * 16 + lr) * BK + ksw];
#pragma unroll
            for (int mi = 0; mi < 4; ++mi) {
                bf16x8 a = *(const bf16x8*)&A[(wm * 64 + mi * 16 + lr) * BK + ksw];
#pragma unroll
                for (int ni = 0; ni < 8; ++ni)
                    acc[mi][ni] = __builtin_amdgcn_mfma_f32_16x16x32_bf16(a, bfr[ni], acc[mi][ni], 0, 0, 0);
            }
        };

        const int NK = HID / BK;   // 64
        STAGE(0, 0); STAGE(1, 1);
        int c0 = 0, c1 = 1, c2 = 2;
        for (int kt = 0; kt < NK; ++kt) {
            SB0();
            if (kt + 1 < NK) { VMCNT4(); } else { VMCNT0(); }
            __builtin_amdgcn_s_barrier();
            SB0();
            if (kt + 2 < NK) STAGE(c2, kt + 2);
            SB0();
            COMPUTE(c0);
            int t = c0; c0 = c1; c1 = c2; c2 = t;
        }
        __syncthreads();

        // epilogue: up waves (wn=1) park u in smem as [256][128] bf16; gate waves combine
        if (wn == 1) {
#pragma unroll
            for (int mi = 0; mi < 4; ++mi)
#pragma unroll
                for (int ni = 0; ni < 8; ++ni)
#pragma unroll
                    for (int rr = 0; rr < 4; ++rr) {
                        int row = wm * 64 + mi * 16 + lg * 4 + rr;
                        int col = ni * 16 + lr;
                        smem[row * 128 + col] = (bf16_t)acc[mi][ni][rr];
                    }
        }
        __syncthreads();
        if (wn == 0) {
#pragma unroll
            for (int mi = 0; mi < 4; ++mi)
#pragma unroll
                for (int ni = 0; ni < 8; ++ni)
#pragma unroll
                    for (int rr = 0; rr < 4; ++rr) {
                        int row = wm * 64 + mi * 16 + lg * 4 + rr;
                        int col = ni * 16 + lr;
                        float g = acc[mi][ni][rr];
                        float u = (float)smem[row * 128 + col];
                        float h = (g / (1.f + __expf(-g))) * u;
                        if (row < nvalid)
                            h_buf[(size_t)(row0 + row) * FINT + f0 + col] = (bf16_t)h;
                    }
        }
        __syncthreads();
    }
}

// ======== down GEMM: 256 slots x 256 h-cols, 8 waves, XCD-affine ========
__global__ __launch_bounds__(512, 2) void down3_kernel(
    const bf16_t* __restrict__ h_buf, const bf16_t* __restrict__ wdb,
    const int* __restrict__ offs,
    const int* __restrict__ dbase, const int* __restrict__ dcount, const int* __restrict__ dn,
    bf16_t* __restrict__ y_buf)
{
    __shared__ bf16_t smem[49152];
    const int tid = threadIdx.x;
    const int lane = tid & 63, w = tid >> 6;
    const int wm = w >> 1, wn = w & 1;
    const int lr = lane & 15, lg = lane >> 4;
    const int rl = lane >> 2;
    const int sw8 = ((lane & 3) ^ ((lane >> 3) & 3)) * 8;
    const int ksw = (lg ^ ((lr >> 1) & 3)) * 8;

    const int xcd = blockIdx.x & 7, slot = blockIdx.x >> 3;
    const int icnt = dcount[xcd], ib = dbase[xcd];

    for (int ii = slot; ii < icnt; ii += 32) {
        const int it = dn[ib + ii];
        const int e = it >> 10, hp = (it >> 6) & 15, tr = it & 63;
        const int seg0 = offs[e];
        const int rbase = tr * TM;
        const int nvalid = min(offs[e + 1] - seg0 - rbase, TM);
        const int row0 = seg0 + rbase;
        const int h0 = hp * 256;

        const bf16_t* aP[2];
#pragma unroll
        for (int i = 0; i < 2; ++i) {
            int r = (w * 2 + i) * 16 + rl;
            aP[i] = h_buf + (size_t)(row0 + r) * FINT + sw8;
        }
        const bf16_t* bP[2];
#pragma unroll
        for (int i = 0; i < 2; ++i) {
            int br = (w * 2 + i) * 16 + rl;                 // h-col within panel
            bP[i] = wdb + ((size_t)e * HID + h0 + br) * FINT + sw8;
        }

        f32x4 acc[4][8];
#pragma unroll
        for (int mi = 0; mi < 4; ++mi)
#pragma unroll
            for (int ni = 0; ni < 8; ++ni) acc[mi][ni] = (f32x4){0.f, 0.f, 0.f, 0.f};

        auto STAGE = [&](int b, int kt) {
            int k0 = kt * BK;
            bf16_t* A = smem + b * 8192;
            bf16_t* B = smem + 24576 + b * 8192;
            gll16(aP[0] + k0, A + (w * 2 + 0) * 512);
            gll16(aP[1] + k0, A + (w * 2 + 1) * 512);
            gll16(bP[0] + k0, B + (w * 2 + 0) * 512);
            gll16(bP[1] + k0, B + (w * 2 + 1) * 512);
        };
        auto COMPUTE = [&](int b) {
            const bf16_t* A = smem + b * 8192;
            const bf16_t* B = smem + 24576 + b * 8192;
            bf16x8 bfr[8];
#pragma unroll
            for (int ni = 0; ni < 8; ++ni)
                bfr[ni] = *(const bf16x8*)&B[(wn * 128 + ni * 16 + lr) * BK + ksw];
#pragma unroll
            for (int mi = 0; mi < 4; ++mi) {
                bf16x8 a = *(const bf16x8*)&A[(wm * 64 + mi * 16 + lr) * BK + ksw];
#pragma unroll
                for (int ni = 0; ni < 8; ++ni)
                    acc[mi][ni] = __builtin_amdgcn_mfma_f32_16x16x32_bf16(a, bfr[ni], acc[mi][ni], 0, 0, 0);
            }
        };

        const int NK = FINT / BK;  // 44
        STAGE(0, 0); STAGE(1, 1);
        int c0 = 0, c1 = 1, c2 = 2;
        for (int kt = 0; kt < NK; ++kt) {
            SB0();
            if (kt + 1 < NK) { VMCNT4(); } else { VMCNT0(); }
            __builtin_amdgcn_s_barrier();
            SB0();
            if (kt + 2 < NK) STAGE(c2, kt + 2);
            SB0();
            COMPUTE(c0);
            int t = c0; c0 = c1; c1 = c2; c2 = t;
        }

#pragma unroll
        for (int mi = 0; mi < 4; ++mi)
#pragma unroll
            for (int ni = 0; ni < 8; ++ni)
#pragma unroll
                for (int rr = 0; rr < 4; ++rr) {
                    int row = wm * 64 + mi * 16 + lg * 4 + rr;
                    int col = wn * 128 + ni * 16 + lr;
                    if (row < nvalid)
                        y_buf[(size_t)(row0 + row) * HID + h0 + col] = (bf16_t)acc[mi][ni][rr];
                }
        __syncthreads();
    }
}

// ---------------- combine: out[t] = w0*y[s0] + w1*y[s1] ----------------
__global__ __launch_bounds__(256) void combine_kernel(
    const bf16_t* __restrict__ y, const int* __restrict__ slot_of,
    const float* __restrict__ topk_w, float* __restrict__ out, int T)
{
    int t = blockIdx.x;
    int tid = threadIdx.x;
    int s0 = slot_of[t * 2], s1 = slot_of[t * 2 + 1];
    float w0 = topk_w[t * 2], w1 = topk_w[t * 2 + 1];
    const bf16x8* y0 = (const bf16x8*)(y + (size_t)s0 * HID);
    const bf16x8* y1 = (const bf16x8*)(y + (size_t)s1 * HID);
    bf16x8 v0 = y0[tid], v1 = y1[tid];
    float* op = out + (size_t)t * HID + tid * 8;
#pragma unroll
    for (int j = 0; j < 8; ++j)
        op[j] = w0 * (float)v0[j] + w1 * (float)v1[j];
}

extern "C" void kernel_launch(void* const* d_in, const int* in_sizes, int n_in,
                              void* d_out, int out_size, void* d_ws, size_t ws_size,
                              hipStream_t stream)
{
    const float* x  = (const float*)d_in[0];
    const float* gw = (const float*)d_in[1];
    const float* wg = (const float*)d_in[2];
    const float* wu = (const float*)d_in[3];
    const float* wd = (const float*)d_in[4];
    float* out = (float*)d_out;
    int T = in_sizes[0] / HID;     // 4096
    int S2 = 2 * T;

    char* base = (char*)d_ws;
    int* cnt     = (int*)base;                 // 8
    int* fill    = cnt + 8;                    // 8
    int* offs    = cnt + 16;                   // 9 (pad to 16)
    int* gbase   = cnt + 32;                   // 8
    int* gcount  = cnt + 40;                   // 8
    int* dbase   = cnt + 48;                   // 8
    int* dcount  = cnt + 56;                   // 8
    int* gu      = cnt + 64;                   // <= 512
    int* dnl     = cnt + 576;                  // <= 384
    int* topk_id = cnt + 960;                  // 2T
    float* topk_w = (float*)(topk_id + S2);    // 2T
    int* tok     = (int*)(topk_w + S2);        // 2T (+256 pad)
    int* slot_of = tok + S2 + 256;             // 2T
    size_t small_end = (size_t)((char*)(slot_of + S2) - base);
    size_t cur = (small_end + 255) & ~(size_t)255;
    auto take = [&](size_t bytes) -> size_t {
        size_t o = cur; cur += bytes; cur = (cur + 255) & ~(size_t)255; return o;
    };
    size_t wbytes = (size_t)NEXP * HID * FINT * 2;
    size_t o_xb  = take((size_t)T * HID * 2);
    size_t o_wgb = take(wbytes);
    size_t o_wub = take(wbytes);
    size_t o_wdb = take(wbytes);
    size_t o_h   = take((size_t)(S2 + 256) * FINT * 2);
    size_t o_y   = take((size_t)(S2 + 256) * HID * 2);
    (void)ws_size;

    bf16_t* xb    = (bf16_t*)(base + o_xb);
    bf16_t* wgb   = (bf16_t*)(base + o_wgb);
    bf16_t* wub   = (bf16_t*)(base + o_wub);
    bf16_t* wdb   = (bf16_t*)(base + o_wdb);
    bf16_t* h_buf = (bf16_t*)(base + o_h);
    bf16_t* y_buf = (bf16_t*)(base + o_y);

    hipMemsetAsync(base, 0, 64, stream);   // cnt + fill

    router_kernel<<<T, 64, 0, stream>>>(x, gw, cnt, topk_id, topk_w, xb, T);
    offsets_kernel<<<1, 64, 0, stream>>>(cnt, offs, gbase, gcount, dbase, dcount, gu, dnl);
    scatter_kernel<<<(T + 255) / 256, 256, 0, stream>>>(topk_id, offs, fill, tok, slot_of, T);

    int gridW = NEXP * (HID / 64) * (FINT / 64);   // 5632
    cvt_t_kernel<<<gridW, 256, 0, stream>>>(wg, wgb, HID, FINT);   // [E][F][H]
    cvt_t_kernel<<<gridW, 256, 0, stream>>>(wu, wub, HID, FINT);   // [E][F][H]
    cvt_t_kernel<<<gridW, 256, 0, stream>>>(wd, wdb, FINT, HID);   // [E][H][F]

    gateup3_kernel<<<256, 512, 0, stream>>>(xb, wgb, wub, offs, tok, gbase, gcount, gu, h_buf);
    down3_kernel<<<256, 512, 0, stream>>>(h_buf, wdb, offs, dbase, dcount, dnl, y_buf);
    combine_kernel<<<T, 256, 0, stream>>>(y_buf, slot_of, topk_w, out, T);
}

// Round 7
// 469.375 us; speedup vs baseline: 3.2043x; 1.0513x over previous
//
#include <hip/hip_runtime.h>
#include <hip/hip_bf16.h>

#define HID  2048
#define NEXP 8
#define FINT 1408
#define TM   256        // slot-tile (M)
#define BK   32
#define GU_NPAN 88      // 8 experts x 11 f-panels (128 f each -> gate+up = 256 cols)
#define DN_NPAN 64      // 8 experts x 8 h-panels (256 h each)

typedef __bf16 bf16_t;
typedef __bf16 bf16x8 __attribute__((ext_vector_type(8)));
typedef float  f32x4  __attribute__((ext_vector_type(4)));

#define AS1 __attribute__((address_space(1)))
#define AS3 __attribute__((address_space(3)))

__device__ __forceinline__ void gll16(const void* g, void* l) {
    __builtin_amdgcn_global_load_lds((const AS1 void*)g, (AS3 void*)l, 16, 0, 0);
}

#define VMCNT4() asm volatile("s_waitcnt vmcnt(4)" ::: "memory")
#define VMCNT0() asm volatile("s_waitcnt vmcnt(0)" ::: "memory")
#define LGKM0()  asm volatile("s_waitcnt lgkmcnt(0)" ::: "memory")
#define SB0() __builtin_amdgcn_sched_barrier(0)

// ---------------- router: logits -> softmax -> top2 + counts (+ x->bf16) ----------------
__global__ __launch_bounds__(64) void router_kernel(
    const float* __restrict__ x, const float* __restrict__ gw,
    int* __restrict__ cnt, int* __restrict__ topk_id, float* __restrict__ topk_w,
    bf16_t* __restrict__ xb, int T)
{
    int t = blockIdx.x;
    if (t >= T) return;
    int lane = threadIdx.x;
    float acc[NEXP];
#pragma unroll
    for (int e = 0; e < NEXP; ++e) acc[e] = 0.f;
    const float* xr = x + (size_t)t * HID;
    bf16_t* xo = xb + (size_t)t * HID;
    for (int i = lane; i < HID; i += 64) {
        float xv = xr[i];
        xo[i] = (bf16_t)xv;
        const float4* g4 = (const float4*)(gw + (size_t)i * NEXP);
        float4 a = g4[0], b = g4[1];
        acc[0] += xv * a.x; acc[1] += xv * a.y; acc[2] += xv * a.z; acc[3] += xv * a.w;
        acc[4] += xv * b.x; acc[5] += xv * b.y; acc[6] += xv * b.z; acc[7] += xv * b.w;
    }
#pragma unroll
    for (int d = 1; d < 64; d <<= 1) {
#pragma unroll
        for (int e = 0; e < NEXP; ++e) acc[e] += __shfl_xor(acc[e], d, 64);
    }
    float mx = acc[0];
#pragma unroll
    for (int e = 1; e < NEXP; ++e) mx = fmaxf(mx, acc[e]);
    float p[NEXP]; float s = 0.f;
#pragma unroll
    for (int e = 0; e < NEXP; ++e) { p[e] = expf(acc[e] - mx); s += p[e]; }
    float inv = 1.f / s;
    int i1 = 0;
#pragma unroll
    for (int e = 1; e < NEXP; ++e) if (acc[e] > acc[i1]) i1 = e;
    int i2 = (i1 == 0) ? 1 : 0;
#pragma unroll
    for (int e = 0; e < NEXP; ++e) if (e != i1 && acc[e] > acc[i2]) i2 = e;
    if (lane == 0) {
        topk_id[t * 2 + 0] = i1; topk_id[t * 2 + 1] = i2;
        topk_w[t * 2 + 0] = p[i1] * inv; topk_w[t * 2 + 1] = p[i2] * inv;
        atomicAdd(&cnt[i1], 1); atomicAdd(&cnt[i2], 1);
    }
}

// ---------------- offsets + per-XCD panel-affine item lists (parallel by xcd) ----------------
__global__ void offsets_kernel(const int* __restrict__ cnt, int* __restrict__ offs,
                               int* __restrict__ gbase, int* __restrict__ gcount,
                               int* __restrict__ dbase, int* __restrict__ dcount,
                               int* __restrict__ gu, int* __restrict__ dn)
{
    __shared__ int gc[8], dc[8];
    int tid = threadIdx.x;
    if (tid == 0) {
        int s = 0;
        for (int e = 0; e < NEXP; ++e) { offs[e] = s; s += cnt[e]; }
        offs[NEXP] = s;
    }
    if (tid < 8) {
        int c = 0;
        for (int p = tid; p < GU_NPAN; p += 8) { int e = p / 11; c += (cnt[e] + TM - 1) / TM; }
        gc[tid] = c;
    } else if (tid < 16) {
        int x = tid - 8, c = 0;
        for (int p = x; p < DN_NPAN; p += 8) { int e = p >> 3; c += (cnt[e] + TM - 1) / TM; }
        dc[x] = c;
    }
    __syncthreads();
    if (tid < 8) {
        int base = 0;
        for (int i = 0; i < tid; ++i) base += gc[i];
        gbase[tid] = base; gcount[tid] = gc[tid];
        int k = base;
        for (int p = tid; p < GU_NPAN; p += 8) {
            int e = p / 11, fp = p - e * 11;
            int nt = (cnt[e] + TM - 1) / TM;
            for (int t = 0; t < nt; ++t) gu[k++] = (e << 10) | (fp << 6) | t;
        }
    } else if (tid < 16) {
        int x = tid - 8;
        int base = 0;
        for (int i = 0; i < x; ++i) base += dc[i];
        dbase[x] = base; dcount[x] = dc[x];
        int k = base;
        for (int p = x; p < DN_NPAN; p += 8) {
            int e = p >> 3, hp = p & 7;
            int nt = (cnt[e] + TM - 1) / TM;
            for (int t = 0; t < nt; ++t) dn[k++] = (e << 10) | (hp << 6) | t;
        }
    }
}

__global__ void scatter_kernel(
    const int* __restrict__ topk_id, const int* __restrict__ offs, int* __restrict__ fill,
    int* __restrict__ tok, int* __restrict__ slot_of, int T)
{
    int t = blockIdx.x * blockDim.x + threadIdx.x;
    if (t >= T) return;
#pragma unroll
    for (int k = 0; k < 2; ++k) {
        int e = topk_id[t * 2 + k];
        int pos = atomicAdd(&fill[e], 1);
        int slot = offs[e] + pos;
        tok[slot] = t;
        slot_of[t * 2 + k] = slot;
    }
}

// ------- transpose-convert all three weights: fp32 [E][R][C] -> bf16 [E][C][R] -------
__global__ __launch_bounds__(256) void cvt3_kernel(
    const float* __restrict__ wg, const float* __restrict__ wu, const float* __restrict__ wd,
    bf16_t* __restrict__ wgb, bf16_t* __restrict__ wub, bf16_t* __restrict__ wdb)
{
    const int per = NEXP * (HID / 64) * (FINT / 64);   // 5632
    int b = blockIdx.x;
    const float* in; bf16_t* outb; int R, C;
    if (b < per)            { in = wg; outb = wgb; R = HID;  C = FINT; }
    else if (b < 2 * per)   { b -= per; in = wu; outb = wub; R = HID;  C = FINT; }
    else                    { b -= 2 * per; in = wd; outb = wdb; R = FINT; C = HID; }

    int tilesC = C >> 6;
    int perE = (R >> 6) * tilesC;
    int e = b / perE;
    int rem = b - e * perE;
    int tr = rem / tilesC, tc = rem - tr * tilesC;
    const float* src = in + (size_t)e * R * C + (size_t)(tr * 64) * C + tc * 64;
    bf16_t* dst = outb + (size_t)e * R * C + (size_t)(tc * 64) * R + tr * 64;

    __shared__ float tile[64][65];
    int tid = threadIdx.x;
    int rr = tid >> 4;
    int cc = (tid & 15) * 4;
#pragma unroll
    for (int i = 0; i < 4; ++i) {
        float4 v = *(const float4*)(src + (size_t)(rr + i * 16) * C + cc);
        tile[rr + i * 16][cc + 0] = v.x; tile[rr + i * 16][cc + 1] = v.y;
        tile[rr + i * 16][cc + 2] = v.z; tile[rr + i * 16][cc + 3] = v.w;
    }
    __syncthreads();
    int oc = tid >> 2;
    int og = (tid & 3) * 16;
    bf16_t* dp = dst + (size_t)oc * R + og;
    bf16x8 o0, o1;
#pragma unroll
    for (int j = 0; j < 8; ++j) { o0[j] = (bf16_t)tile[og + j][oc]; o1[j] = (bf16_t)tile[og + 8 + j][oc]; }
    *(bf16x8*)dp = o0;
    *(bf16x8*)(dp + 8) = o1;
}

// ======== gate+up GEMM: 256 slots x (128f x {gate,up}), 8 waves, XCD-affine, interleaved ========
__global__ __launch_bounds__(512, 2) void gateup3_kernel(
    const bf16_t* __restrict__ xb, const bf16_t* __restrict__ wgb, const bf16_t* __restrict__ wub,
    const int* __restrict__ offs, const int* __restrict__ tok,
    const int* __restrict__ gbase, const int* __restrict__ gcount, const int* __restrict__ gu,
    bf16_t* __restrict__ h_buf)
{
    __shared__ bf16_t smem[49152];   // A: 3 x 8192, B: 3 x 8192 (96 KB)
    const int tid = threadIdx.x;
    const int lane = tid & 63, w = tid >> 6;      // 8 waves
    const int wm = w >> 1, wn = w & 1;            // 4 x 2 wave grid (64r x 128c each)
    const int lr = lane & 15, lg = lane >> 4;
    const int rl = lane >> 2;
    const int sw8 = ((lane & 3) ^ ((lane >> 3) & 3)) * 8;   // source k pre-swizzle
    const int ksw = (lg ^ ((lr >> 1) & 3)) * 8;             // read-side swizzle

    const int xcd = blockIdx.x & 7, slot = blockIdx.x >> 3;  // 32 slots per xcd
    const int icnt = gcount[xcd], ib = gbase[xcd];

    for (int ii = slot; ii < icnt; ii += 32) {
        const int it = gu[ib + ii];
        const int e = it >> 10, fp = (it >> 6) & 15, tr = it & 63;
        const int seg0 = offs[e];
        const int rbase = tr * TM;
        const int nvalid = min(offs[e + 1] - seg0 - rbase, TM);
        const int row0 = seg0 + rbase;
        const int f0 = fp * 128;

        const bf16_t* aP[2];
#pragma unroll
        for (int i = 0; i < 2; ++i) {
            int r = (w * 2 + i) * 16 + rl;
            int tk = tok[row0 + min(r, nvalid - 1)];
            aP[i] = xb + (size_t)tk * HID + sw8;
        }
        const bf16_t* bP[2];
#pragma unroll
        for (int i = 0; i < 2; ++i) {
            int br = (w * 2 + i) * 16 + rl;                 // 0..255: <128 gate, >=128 up
            const bf16_t* W = (br < 128) ? wgb : wub;
            bP[i] = W + ((size_t)e * FINT + f0 + (br & 127)) * HID + sw8;
        }

        f32x4 acc[4][8];
#pragma unroll
        for (int mi = 0; mi < 4; ++mi)
#pragma unroll
            for (int ni = 0; ni < 8; ++ni) acc[mi][ni] = (f32x4){0.f, 0.f, 0.f, 0.f};

        auto STAGE_A = [&](int b, int kt) {
            int k0 = kt * BK;
            bf16_t* A = smem + b * 8192;
            gll16(aP[0] + k0, A + (w * 2 + 0) * 512);
            gll16(aP[1] + k0, A + (w * 2 + 1) * 512);
        };
        auto STAGE_B = [&](int b, int kt) {
            int k0 = kt * BK;
            bf16_t* B = smem + 24576 + b * 8192;
            gll16(bP[0] + k0, B + (w * 2 + 0) * 512);
            gll16(bP[1] + k0, B + (w * 2 + 1) * 512);
        };

        const int NK = HID / BK;   // 64
        STAGE_A(0, 0); STAGE_B(0, 0); STAGE_A(1, 1); STAGE_B(1, 1);
        int c0 = 0, c1 = 1, c2 = 2;
        for (int kt = 0; kt < NK; ++kt) {
            // top wait: own c0 loads retired (newest 4 = c1 loads may remain);
            // barrier makes every wave's c0 data visible before any read.
            SB0();
            if (kt + 1 < NK) { VMCNT4(); } else { VMCNT0(); }
            __builtin_amdgcn_s_barrier();
            SB0();
            const bf16_t* A = smem + c0 * 8192;
            const bf16_t* B = smem + 24576 + c0 * 8192;
            // ---- phase 0: issue A-stage, read A frags + B half0, MFMA ----
            if (kt + 2 < NK) STAGE_A(c2, kt + 2);
            bf16x8 afr[4], bfr[4];
#pragma unroll
            for (int mi = 0; mi < 4; ++mi)
                afr[mi] = *(const bf16x8*)&A[(wm * 64 + mi * 16 + lr) * BK + ksw];
#pragma unroll
            for (int ni = 0; ni < 4; ++ni)
                bfr[ni] = *(const bf16x8*)&B[(wn * 128 + ni * 16 + lr) * BK + ksw];
            LGKM0(); SB0();
            __builtin_amdgcn_s_setprio(1);
#pragma unroll
            for (int mi = 0; mi < 4; ++mi)
#pragma unroll
                for (int ni = 0; ni < 4; ++ni)
                    acc[mi][ni] = __builtin_amdgcn_mfma_f32_16x16x32_bf16(afr[mi], bfr[ni], acc[mi][ni], 0, 0, 0);
            __builtin_amdgcn_s_setprio(0);
            SB0();
            // ---- phase 1: issue B-stage, read B half1, MFMA ----
            if (kt + 2 < NK) STAGE_B(c2, kt + 2);
#pragma unroll
            for (int ni = 0; ni < 4; ++ni)
                bfr[ni] = *(const bf16x8*)&B[(wn * 128 + (ni + 4) * 16 + lr) * BK + ksw];
            LGKM0(); SB0();
            __builtin_amdgcn_s_setprio(1);
#pragma unroll
            for (int mi = 0; mi < 4; ++mi)
#pragma unroll
                for (int ni = 0; ni < 4; ++ni)
                    acc[mi][ni + 4] = __builtin_amdgcn_mfma_f32_16x16x32_bf16(afr[mi], bfr[ni], acc[mi][ni + 4], 0, 0, 0);
            __builtin_amdgcn_s_setprio(0);
            SB0();
            int t = c0; c0 = c1; c1 = c2; c2 = t;
        }
        __syncthreads();

        // epilogue: up waves (wn=1) park u in smem as [256][128] bf16; gate waves combine
        if (wn == 1) {
#pragma unroll
            for (int mi = 0; mi < 4; ++mi)
#pragma unroll
                for (int ni = 0; ni < 8; ++ni)
#pragma unroll
                    for (int rr = 0; rr < 4; ++rr) {
                        int row = wm * 64 + mi * 16 + lg * 4 + rr;
                        int col = ni * 16 + lr;
                        smem[row * 128 + col] = (bf16_t)acc[mi][ni][rr];
                    }
        }
        __syncthreads();
        if (wn == 0) {
#pragma unroll
            for (int mi = 0; mi < 4; ++mi)
#pragma unroll
                for (int ni = 0; ni < 8; ++ni)
#pragma unroll
                    for (int rr = 0; rr < 4; ++rr) {
                        int row = wm * 64 + mi * 16 + lg * 4 + rr;
                        int col = ni * 16 + lr;
                        float g = acc[mi][ni][rr];
                        float u = (float)smem[row * 128 + col];
                        float h = (g / (1.f + __expf(-g))) * u;
                        if (row < nvalid)
                            h_buf[(size_t)(row0 + row) * FINT + f0 + col] = (bf16_t)h;
                    }
        }
        __syncthreads();
    }
}

// ======== down GEMM: 256 slots x 256 h-cols, 8 waves, XCD-affine, interleaved ========
__global__ __launch_bounds__(512, 2) void down3_kernel(
    const bf16_t* __restrict__ h_buf, const bf16_t* __restrict__ wdb,
    const int* __restrict__ offs,
    const int* __restrict__ dbase, const int* __restrict__ dcount, const int* __restrict__ dn,
    bf16_t* __restrict__ y_buf)
{
    __shared__ bf16_t smem[49152];
    const int tid = threadIdx.x;
    const int lane = tid & 63, w = tid >> 6;
    const int wm = w >> 1, wn = w & 1;
    const int lr = lane & 15, lg = lane >> 4;
    const int rl = lane >> 2;
    const int sw8 = ((lane & 3) ^ ((lane >> 3) & 3)) * 8;
    const int ksw = (lg ^ ((lr >> 1) & 3)) * 8;

    const int xcd = blockIdx.x & 7, slot = blockIdx.x >> 3;
    const int icnt = dcount[xcd], ib = dbase[xcd];

    for (int ii = slot; ii < icnt; ii += 32) {
        const int it = dn[ib + ii];
        const int e = it >> 10, hp = (it >> 6) & 15, tr = it & 63;
        const int seg0 = offs[e];
        const int rbase = tr * TM;
        const int nvalid = min(offs[e + 1] - seg0 - rbase, TM);
        const int row0 = seg0 + rbase;
        const int h0 = hp * 256;

        const bf16_t* aP[2];
#pragma unroll
        for (int i = 0; i < 2; ++i) {
            int r = (w * 2 + i) * 16 + rl;
            aP[i] = h_buf + (size_t)(row0 + r) * FINT + sw8;
        }
        const bf16_t* bP[2];
#pragma unroll
        for (int i = 0; i < 2; ++i) {
            int br = (w * 2 + i) * 16 + rl;                 // h-col within panel
            bP[i] = wdb + ((size_t)e * HID + h0 + br) * FINT + sw8;
        }

        f32x4 acc[4][8];
#pragma unroll
        for (int mi = 0; mi < 4; ++mi)
#pragma unroll
            for (int ni = 0; ni < 8; ++ni) acc[mi][ni] = (f32x4){0.f, 0.f, 0.f, 0.f};

        auto STAGE_A = [&](int b, int kt) {
            int k0 = kt * BK;
            bf16_t* A = smem + b * 8192;
            gll16(aP[0] + k0, A + (w * 2 + 0) * 512);
            gll16(aP[1] + k0, A + (w * 2 + 1) * 512);
        };
        auto STAGE_B = [&](int b, int kt) {
            int k0 = kt * BK;
            bf16_t* B = smem + 24576 + b * 8192;
            gll16(bP[0] + k0, B + (w * 2 + 0) * 512);
            gll16(bP[1] + k0, B + (w * 2 + 1) * 512);
        };

        const int NK = FINT / BK;  // 44
        STAGE_A(0, 0); STAGE_B(0, 0); STAGE_A(1, 1); STAGE_B(1, 1);
        int c0 = 0, c1 = 1, c2 = 2;
        for (int kt = 0; kt < NK; ++kt) {
            SB0();
            if (kt + 1 < NK) { VMCNT4(); } else { VMCNT0(); }
            __builtin_amdgcn_s_barrier();
            SB0();
            const bf16_t* A = smem + c0 * 8192;
            const bf16_t* B = smem + 24576 + c0 * 8192;
            // ---- phase 0 ----
            if (kt + 2 < NK) STAGE_A(c2, kt + 2);
            bf16x8 afr[4], bfr[4];
#pragma unroll
            for (int mi = 0; mi < 4; ++mi)
                afr[mi] = *(const bf16x8*)&A[(wm * 64 + mi * 16 + lr) * BK + ksw];
#pragma unroll
            for (int ni = 0; ni < 4; ++ni)
                bfr[ni] = *(const bf16x8*)&B[(wn * 128 + ni * 16 + lr) * BK + ksw];
            LGKM0(); SB0();
            __builtin_amdgcn_s_setprio(1);
#pragma unroll
            for (int mi = 0; mi < 4; ++mi)
#pragma unroll
                for (int ni = 0; ni < 4; ++ni)
                    acc[mi][ni] = __builtin_amdgcn_mfma_f32_16x16x32_bf16(afr[mi], bfr[ni], acc[mi][ni], 0, 0, 0);
            __builtin_amdgcn_s_setprio(0);
            SB0();
            // ---- phase 1 ----
            if (kt + 2 < NK) STAGE_B(c2, kt + 2);
#pragma unroll
            for (int ni = 0; ni < 4; ++ni)
                bfr[ni] = *(const bf16x8*)&B[(wn * 128 + (ni + 4) * 16 + lr) * BK + ksw];
            LGKM0(); SB0();
            __builtin_amdgcn_s_setprio(1);
#pragma unroll
            for (int mi = 0; mi < 4; ++mi)
#pragma unroll
                for (int ni = 0; ni < 4; ++ni)
                    acc[mi][ni + 4] = __builtin_amdgcn_mfma_f32_16x16x32_bf16(afr[mi], bfr[ni], acc[mi][ni + 4], 0, 0, 0);
            __builtin_amdgcn_s_setprio(0);
            SB0();
            int t = c0; c0 = c1; c1 = c2; c2 = t;
        }

#pragma unroll
        for (int mi = 0; mi < 4; ++mi)
#pragma unroll
            for (int ni = 0; ni < 8; ++ni)
#pragma unroll
                for (int rr = 0; rr < 4; ++rr) {
                    int row = wm * 64 + mi * 16 + lg * 4 + rr;
                    int col = wn * 128 + ni * 16 + lr;
                    if (row < nvalid)
                        y_buf[(size_t)(row0 + row) * HID + h0 + col] = (bf16_t)acc[mi][ni][rr];
                }
        __syncthreads();
    }
}

// ---------------- combine: out[t] = w0*y[s0] + w1*y[s1] ----------------
__global__ __launch_bounds__(256) void combine_kernel(
    const bf16_t* __restrict__ y, const int* __restrict__ slot_of,
    const float* __restrict__ topk_w, float* __restrict__ out, int T)
{
    int t = blockIdx.x;
    int tid = threadIdx.x;
    int s0 = slot_of[t * 2], s1 = slot_of[t * 2 + 1];
    float w0 = topk_w[t * 2], w1 = topk_w[t * 2 + 1];
    const bf16x8* y0 = (const bf16x8*)(y + (size_t)s0 * HID);
    const bf16x8* y1 = (const bf16x8*)(y + (size_t)s1 * HID);
    bf16x8 v0 = y0[tid], v1 = y1[tid];
    float* op = out + (size_t)t * HID + tid * 8;
#pragma unroll
    for (int j = 0; j < 8; ++j)
        op[j] = w0 * (float)v0[j] + w1 * (float)v1[j];
}

extern "C" void kernel_launch(void* const* d_in, const int* in_sizes, int n_in,
                              void* d_out, int out_size, void* d_ws, size_t ws_size,
                              hipStream_t stream)
{
    const float* x  = (const float*)d_in[0];
    const float* gw = (const float*)d_in[1];
    const float* wg = (const float*)d_in[2];
    const float* wu = (const float*)d_in[3];
    const float* wd = (const float*)d_in[4];
    float* out = (float*)d_out;
    int T = in_sizes[0] / HID;     // 4096
    int S2 = 2 * T;

    char* base = (char*)d_ws;
    int* cnt     = (int*)base;                 // 8
    int* fill    = cnt + 8;                    // 8
    int* offs    = cnt + 16;                   // 9 (pad to 16)
    int* gbase   = cnt + 32;                   // 8
    int* gcount  = cnt + 40;                   // 8
    int* dbase   = cnt + 48;                   // 8
    int* dcount  = cnt + 56;                   // 8
    int* gu      = cnt + 64;                   // <= 512
    int* dnl     = cnt + 576;                  // <= 384
    int* topk_id = cnt + 960;                  // 2T
    float* topk_w = (float*)(topk_id + S2);    // 2T
    int* tok     = (int*)(topk_w + S2);        // 2T (+256 pad)
    int* slot_of = tok + S2 + 256;             // 2T
    size_t small_end = (size_t)((char*)(slot_of + S2) - base);
    size_t cur = (small_end + 255) & ~(size_t)255;
    auto take = [&](size_t bytes) -> size_t {
        size_t o = cur; cur += bytes; cur = (cur + 255) & ~(size_t)255; return o;
    };
    size_t wbytes = (size_t)NEXP * HID * FINT * 2;
    size_t o_xb  = take((size_t)T * HID * 2);
    size_t o_wgb = take(wbytes);
    size_t o_wub = take(wbytes);
    size_t o_wdb = take(wbytes);
    size_t o_h   = take((size_t)(S2 + 256) * FINT * 2);
    size_t o_y   = take((size_t)(S2 + 256) * HID * 2);
    (void)ws_size;

    bf16_t* xb    = (bf16_t*)(base + o_xb);
    bf16_t* wgb   = (bf16_t*)(base + o_wgb);
    bf16_t* wub   = (bf16_t*)(base + o_wub);
    bf16_t* wdb   = (bf16_t*)(base + o_wdb);
    bf16_t* h_buf = (bf16_t*)(base + o_h);
    bf16_t* y_buf = (bf16_t*)(base + o_y);

    hipMemsetAsync(base, 0, 64, stream);   // cnt + fill

    router_kernel<<<T, 64, 0, stream>>>(x, gw, cnt, topk_id, topk_w, xb, T);
    offsets_kernel<<<1, 64, 0, stream>>>(cnt, offs, gbase, gcount, dbase, dcount, gu, dnl);
    scatter_kernel<<<(T + 255) / 256, 256, 0, stream>>>(topk_id, offs, fill, tok, slot_of, T);

    int gridW = 3 * NEXP * (HID / 64) * (FINT / 64);   // 16896
    cvt3_kernel<<<gridW, 256, 0, stream>>>(wg, wu, wd, wgb, wub, wdb);

    gateup3_kernel<<<256, 512, 0, stream>>>(xb, wgb, wub, offs, tok, gbase, gcount, gu, h_buf);
    down3_kernel<<<256, 512, 0, stream>>>(h_buf, wdb, offs, dbase, dcount, dnl, y_buf);
    combine_kernel<<<T, 256, 0, stream>>>(y_buf, slot_of, topk_w, out, T);
}